// Round 2
// baseline (7586.529 us; speedup 1.0000x reference)
//
#include <hip/hip_runtime.h>
#include <math.h>

#define DEV __device__ __forceinline__

// ---- problem constants ----
#define PP    256          // pairs
#define BIMG  16
#define HB    712          // bilinear dim
#define KBIL  (712*712)    // 506944
#define DRELC 1936

// ---- d_out layout (floats) ----
#define SZ_ACT    (16*157)
#define OFF_ACT   0
#define OFF_POOLED (SZ_ACT)
#define SZ_POOLED (16*1936)
#define OFF_MEM   (OFF_POOLED + SZ_POOLED)
#define SZ_MEM    (24*16*1936)
#define OFF_MASK  (OFF_MEM + SZ_MEM)
#define SZ_MASK   (16*24)

// ---- ws layout (floats) ----
// x1 (conv1 output) is dead after pool_k; pvr/pbil are only live after it.
// They share one region to keep the footprint ~50 MB.
#define OFF_S     0
#define OFF_O     (OFF_S + 256*712)
#define OFF_Z1    (OFF_O + 256*712)
#define OFF_BIL   (OFF_Z1 + 256*712)
#define OFF_REL   (OFF_BIL + 256*712)
#define OFF_UBUF  (OFF_REL + 256*1936)
#define OFF_XP    (OFF_UBUF + 12544*256)
#define OFF_SHARED (OFF_XP + 256*128*49)
#define OFF_X1    OFF_SHARED                       // 256*128*196 floats
#define OFF_PVR   OFF_SHARED                       // 8*256*512
#define OFF_PBIL  (OFF_PVR + 8*256*512)            // 24*256*712
#define SZ_SHARED (256*128*196)                    // max(x1, pvr+pbil)
#define OFF_INTS  (OFF_SHARED + SZ_SHARED)

struct GP {
  const float* A; const float* A2; const float* B; const float* bias;
  float* C;
  const int* gidx; int goff;
  int M, N, K;
  int ldc, coff;
  int kChunk;
  const float* bn_g; const float* bn_b; const float* bn_m; const float* bn_v;
};

// modes:
// 0: A row-gathered via gidx (features)         epi: +bias -> C
// 2: plain A, B = vr_w gather (k = q*256+oc)    epi: partial C[z][M][N]
// 3: A = concat(s,o)                            epi: +bias -> C
// 4: A = relu(concat(z1,bil))                   epi: +bias -> C
// 5: A = union_feat gather [(n,q)][ic]          epi: +bias -> C
// 6: A = im2col(xp) 3x3 pad1                    epi: bn2(relu(+bias)) += C
// 7: A[n,k] = s[n,k/712]*o[n,k%712]             epi: partial C[z][M][N]
// 8: plain A                                    epi: sigmoid(+bias) -> C

template<int MODE>
DEV float loadA(const GP& p, int r, int k) {
  if (MODE == 0) { int fr = p.gidx[2*r + p.goff]; return p.A[fr*2048 + k]; }
  if (MODE == 2 || MODE == 8) return p.A[r*p.K + k];
  if (MODE == 3) return (k < 712) ? p.A[r*712 + k] : p.A2[r*712 + (k-712)];
  if (MODE == 4) { float v = (k < 712) ? p.A[r*712 + k] : p.A2[r*712 + (k-712)];
                   return fmaxf(v, 0.f); }
  if (MODE == 5) { int n = r/49, q = r - n*49; return p.A[(n*1024 + k)*49 + q]; }
  if (MODE == 6) {
    int n = r/49, q = r - n*49; int py = q/7, px = q - py*7;
    int ic = k/9, k9 = k - ic*9; int dy = k9/3, dx = k9 - dy*3;
    int iy = py + dy - 1, ix = px + dx - 1;
    if ((unsigned)iy >= 7u || (unsigned)ix >= 7u) return 0.f;
    return p.A[(n*128 + ic)*49 + iy*7 + ix];
  }
  if (MODE == 7) { int h = k/712, t = k - h*712; return p.A[r*712 + h] * p.A2[r*712 + t]; }
  return 0.f;
}

template<int MODE>
DEV float loadB(const GP& p, int c, int k) {
  if (MODE == 2) { int q = k >> 8, oc = k & 255; return p.B[c*12544 + oc*49 + q]; }
  return p.B[c*p.K + k];
}

template<int MODE>
__global__ __launch_bounds__(256) void gemm_k(GP p) {
  __shared__ float As[16][68];
  __shared__ float Bs[16][68];
  const int tid = threadIdx.x;
  const int tx = tid & 15, ty = tid >> 4;
  const int col0 = blockIdx.x * 64, row0 = blockIdx.y * 64;
  const int kStart = blockIdx.z * p.kChunk;
  const int kEnd = min(p.K, kStart + p.kChunk);
  float acc[4][4] = {};

  for (int kb = kStart; kb < kEnd; kb += 16) {
    // ---- stage A ----
    if (MODE == 5 || MODE == 6) {           // row-contiguous source: lanes along rows
      int r = tid & 63, kk0 = tid >> 6;
      #pragma unroll
      for (int i = 0; i < 4; i++) {
        int kk = kk0 + i*4;
        int gr = row0 + r, gk = kb + kk;
        float v = 0.f;
        if (gr < p.M && gk < kEnd) v = loadA<MODE>(p, gr, gk);
        As[kk][r] = v;
      }
    } else {                                 // k-contiguous source: lanes along k
      int kk = tid & 15, r0 = tid >> 4;
      #pragma unroll
      for (int i = 0; i < 4; i++) {
        int r = r0 + i*16;
        int gr = row0 + r, gk = kb + kk;
        float v = 0.f;
        if (gr < p.M && gk < kEnd) v = loadA<MODE>(p, gr, gk);
        As[kk][r] = v;
      }
    }
    // ---- stage B ----
    {
      int kk = tid & 15, c0 = tid >> 4;
      #pragma unroll
      for (int i = 0; i < 4; i++) {
        int c = c0 + i*16;
        int gc = col0 + c, gk = kb + kk;
        float v = 0.f;
        if (gc < p.N && gk < kEnd) v = loadB<MODE>(p, gc, gk);
        Bs[kk][c] = v;
      }
    }
    __syncthreads();
    #pragma unroll
    for (int kk = 0; kk < 16; kk++) {
      float a[4], b[4];
      #pragma unroll
      for (int j = 0; j < 4; j++) a[j] = As[kk][ty*4 + j];
      #pragma unroll
      for (int j = 0; j < 4; j++) b[j] = Bs[kk][tx*4 + j];
      #pragma unroll
      for (int i = 0; i < 4; i++)
        #pragma unroll
        for (int j = 0; j < 4; j++) acc[i][j] += a[i]*b[j];
    }
    __syncthreads();
  }

  // ---- epilogue ----
  #pragma unroll
  for (int i = 0; i < 4; i++) {
    int r = row0 + ty*4 + i;
    if (r >= p.M) continue;
    #pragma unroll
    for (int j = 0; j < 4; j++) {
      int c = col0 + tx*4 + j;
      if (c >= p.N) continue;
      float v = acc[i][j];
      if (MODE == 2 || MODE == 7) {
        p.C[(size_t)blockIdx.z * p.M * p.N + (size_t)r * p.N + c] = v;
      } else if (MODE == 6) {
        float sc = p.bn_g[c] / sqrtf(p.bn_v[c] + 1e-5f);
        float sh = p.bn_b[c] - p.bn_m[c]*sc;
        float t2 = fmaxf(v + p.bias[c], 0.f)*sc + sh;
        p.C[r*p.ldc + p.coff + c] += t2;
      } else if (MODE == 8) {
        float t2 = v + p.bias[c];
        p.C[r*p.ldc + p.coff + c] = 1.f/(1.f + expf(-t2));
      } else {
        p.C[r*p.ldc + p.coff + c] = v + p.bias[c];
      }
    }
  }
}

__global__ __launch_bounds__(256) void reduce_k(const float* __restrict__ part,
    const float* __restrict__ bias, float* __restrict__ out,
    int S, int MN, int N, int ldc, int coff) {
  int i = blockIdx.x*256 + threadIdx.x;
  if (i >= MN) return;
  float s = 0.f;
  for (int z = 0; z < S; z++) s += part[(size_t)z*MN + i];
  int r = i / N, c = i - r*N;
  out[r*ldc + coff + c] = s + bias[c];
}

__global__ __launch_bounds__(256) void emb_k(const int* __restrict__ pi,
    const int* __restrict__ labels, const float* __restrict__ e1,
    const float* __restrict__ e2, float* __restrict__ s, float* __restrict__ o) {
  int i = blockIdx.x*256 + threadIdx.x;
  if (i >= 2*256*200) return;
  int which = i / (256*200); int rest = i - which*(256*200);
  int n = rest / 200; int j = rest - n*200;
  int lab = labels[pi[2*n + which]];
  float v = which ? e2[lab*200 + j] : e1[lab*200 + j];
  (which ? o : s)[n*712 + 512 + j] = v;
}

__global__ __launch_bounds__(256) void conv1_k(const float* __restrict__ in,
    const float* __restrict__ w, const float* __restrict__ bias,
    const float* __restrict__ g, const float* __restrict__ bt,
    const float* __restrict__ m, const float* __restrict__ vv,
    float* __restrict__ out) {
  int idx = blockIdx.x*256 + threadIdx.x;
  if (idx >= 256*128*14) return;
  int oy = idx % 14; int t = idx / 14; int c = t & 127; int n = t >> 7;
  float acc[14];
  float b0 = bias[c];
  #pragma unroll
  for (int ox = 0; ox < 14; ox++) acc[ox] = b0;
  for (int ci = 0; ci < 2; ci++) {
    #pragma unroll
    for (int ky = 0; ky < 7; ky++) {
      int iy = oy*2 - 3 + ky;
      if ((unsigned)iy >= 27u) continue;
      const float* ir = in + ((n*2 + ci)*27 + iy)*27;
      const float* wr = w + ((c*2 + ci)*7 + ky)*7;
      float iv[27];
      #pragma unroll
      for (int x = 0; x < 27; x++) iv[x] = ir[x];
      float wk[7];
      #pragma unroll
      for (int kx = 0; kx < 7; kx++) wk[kx] = wr[kx];
      #pragma unroll
      for (int kx = 0; kx < 7; kx++)
        #pragma unroll
        for (int ox = 0; ox < 14; ox++) {
          int ix = ox*2 - 3 + kx;
          if (ix >= 0 && ix < 27) acc[ox] += iv[ix]*wk[kx];
        }
    }
  }
  float sc = g[c] / sqrtf(vv[c] + 1e-5f);
  float sh = bt[c] - m[c]*sc;
  float* orow = out + ((n*128 + c)*14 + oy)*14;
  #pragma unroll
  for (int ox = 0; ox < 14; ox++) orow[ox] = fmaxf(acc[ox], 0.f)*sc + sh;
}

__global__ __launch_bounds__(256) void pool_k(const float* __restrict__ x1,
                                              float* __restrict__ xp) {
  int idx = blockIdx.x*256 + threadIdx.x;
  if (idx >= 256*128*49) return;
  int px = idx % 7; int t = idx / 7; int py = t % 7; t /= 7;
  int c = t & 127; int n = t >> 7;
  float mx = -INFINITY;
  for (int dy = 0; dy < 3; dy++) {
    int y = py*2 - 1 + dy;
    if ((unsigned)y >= 14u) continue;
    for (int dx = 0; dx < 3; dx++) {
      int x = px*2 - 1 + dx;
      if ((unsigned)x >= 14u) continue;
      mx = fmaxf(mx, x1[((n*128 + c)*14 + y)*14 + x]);
    }
  }
  xp[((n*128 + c)*7 + py)*7 + px] = mx;
}

__global__ __launch_bounds__(256) void seg_k(const int* __restrict__ im,
    int* __restrict__ counts, int* __restrict__ starts, int* __restrict__ pos) {
  __shared__ int c[16], s[16];
  int tid = threadIdx.x;
  if (tid < 16) c[tid] = 0;
  __syncthreads();
  atomicAdd(&c[im[tid]], 1);
  __syncthreads();
  if (tid == 0) { int run = 0; for (int b = 0; b < 16; b++) { s[b] = run; run += c[b]; } }
  __syncthreads();
  if (tid < 16) { counts[tid] = c[tid]; starts[tid] = s[tid]; }
  pos[tid] = tid - s[im[tid]];
}

__global__ __launch_bounds__(256) void zeromask_k(float* __restrict__ out,
                                                  const int* __restrict__ counts) {
  int i = blockIdx.x*256 + threadIdx.x;
  if (i < SZ_MEM) { out[OFF_MEM + i] = 0.f; return; }
  int j = i - SZ_MEM;
  if (j < SZ_MASK) {
    int b = j / 24, l = j - b*24;
    out[OFF_MASK + j] = (l >= counts[b]) ? 1.f : 0.f;
  }
}

__global__ __launch_bounds__(256) void scatter_k(const float* __restrict__ rel,
    const int* __restrict__ pos, const int* __restrict__ im, float* __restrict__ out) {
  int n = blockIdx.x;
  int l = pos[n], b = im[n];
  float* dst = out + OFF_MEM + ((size_t)l*16 + b)*1936;
  const float* src = rel + (size_t)n*1936;
  for (int d = threadIdx.x; d < 1936; d += 256) dst[d] = src[d];
}

__global__ __launch_bounds__(256) void pooled_k(const float* __restrict__ rel,
    const int* __restrict__ starts, const int* __restrict__ counts,
    float* __restrict__ out) {
  int b = blockIdx.y;
  int d = blockIdx.x*256 + threadIdx.x;
  if (d >= 1936) return;
  int st = starts[b], ct = counts[b];
  float mx = -INFINITY;
  for (int i = 0; i < ct; i++) mx = fmaxf(mx, rel[(size_t)(st + i)*1936 + d]);
  out[OFF_POOLED + b*1936 + d] = mx;
}

extern "C" void kernel_launch(void* const* d_in, const int* in_sizes, int n_in,
                              void* d_out, int out_size, void* d_ws, size_t ws_size,
                              hipStream_t stream) {
  const float* features   = (const float*)d_in[0];
  const int*   pair_idx   = (const int*)d_in[1];
  const int*   im_idx     = (const int*)d_in[2];
  const int*   labels     = (const int*)d_in[3];
  const float* union_feat = (const float*)d_in[4];
  const float* spatial    = (const float*)d_in[5];
  const float* w_union    = (const float*)d_in[6];
  const float* b_union    = (const float*)d_in[7];
  const float* conv1_w    = (const float*)d_in[8];
  const float* conv1_b    = (const float*)d_in[9];
  const float* bn1_g      = (const float*)d_in[10];
  const float* bn1_b      = (const float*)d_in[11];
  const float* bn1_m      = (const float*)d_in[12];
  const float* bn1_v      = (const float*)d_in[13];
  const float* conv2_w    = (const float*)d_in[14];
  const float* conv2_b    = (const float*)d_in[15];
  const float* bn2_g      = (const float*)d_in[16];
  const float* bn2_b      = (const float*)d_in[17];
  const float* bn2_m      = (const float*)d_in[18];
  const float* bn2_v      = (const float*)d_in[19];
  const float* subj_w     = (const float*)d_in[20];
  const float* subj_b     = (const float*)d_in[21];
  const float* obj_w      = (const float*)d_in[22];
  const float* obj_b      = (const float*)d_in[23];
  const float* vr_w       = (const float*)d_in[24];
  const float* vr_b       = (const float*)d_in[25];
  const float* emb1       = (const float*)d_in[26];
  const float* emb2       = (const float*)d_in[27];
  const float* bil_w      = (const float*)d_in[28];
  const float* bil_b      = (const float*)d_in[29];
  const float* lin_w      = (const float*)d_in[30];
  const float* lin_b      = (const float*)d_in[31];
  const float* proj_w     = (const float*)d_in[32];
  const float* proj_b     = (const float*)d_in[33];
  const float* ac_w       = (const float*)d_in[34];
  const float* ac_b       = (const float*)d_in[35];

  float* ws = (float*)d_ws;
  float* s_mat  = ws + OFF_S;
  float* o_mat  = ws + OFF_O;
  float* z1     = ws + OFF_Z1;
  float* bilbuf = ws + OFF_BIL;
  float* rel    = ws + OFF_REL;
  float* ubuf   = ws + OFF_UBUF;
  float* x1     = ws + OFF_X1;
  float* xp     = ws + OFF_XP;
  float* pvr    = ws + OFF_PVR;
  float* pbil   = ws + OFF_PBIL;
  int*   ints   = (int*)(ws + OFF_INTS);
  int* counts = ints; int* starts = ints + 16; int* pos = ints + 32;
  float* out = (float*)d_out;

  dim3 blk(256);

  // subj / obj linears (gathered rows of features) -> s_mat/o_mat cols [0,512)
  {
    GP g{}; g.A = features; g.B = subj_w; g.bias = subj_b; g.C = s_mat;
    g.gidx = pair_idx; g.goff = 0; g.M = 256; g.N = 512; g.K = 2048;
    g.ldc = 712; g.coff = 0; g.kChunk = 2048;
    gemm_k<0><<<dim3(8,4,1), blk, 0, stream>>>(g);
    g.goff = 1; g.B = obj_w; g.bias = obj_b; g.C = o_mat;
    gemm_k<0><<<dim3(8,4,1), blk, 0, stream>>>(g);
  }
  // embedding concat -> cols [512,712)
  emb_k<<<dim3(400), blk, 0, stream>>>(pair_idx, labels, emb1, emb2, s_mat, o_mat);

  // union 1x1 conv as GEMM -> ubuf[(n,q)][oc]
  {
    GP g{}; g.A = union_feat; g.B = w_union; g.bias = b_union; g.C = ubuf;
    g.M = 12544; g.N = 256; g.K = 1024; g.ldc = 256; g.coff = 0; g.kChunk = 1024;
    gemm_k<5><<<dim3(4,196,1), blk, 0, stream>>>(g);
  }

  // conv1 + relu + bn1 -> x1 ; maxpool -> xp
  conv1_k<<<dim3(1792), blk, 0, stream>>>(spatial, conv1_w, conv1_b,
                                          bn1_g, bn1_b, bn1_m, bn1_v, x1);
  pool_k<<<dim3(6272), blk, 0, stream>>>(x1, xp);

  // conv2 (implicit GEMM) + relu + bn2, accumulated into ubuf
  {
    GP g{}; g.A = xp; g.B = conv2_w; g.bias = conv2_b; g.C = ubuf;
    g.M = 12544; g.N = 256; g.K = 1152; g.ldc = 256; g.coff = 0; g.kChunk = 1152;
    g.bn_g = bn2_g; g.bn_b = bn2_b; g.bn_m = bn2_m; g.bn_v = bn2_v;
    gemm_k<6><<<dim3(4,196,1), blk, 0, stream>>>(g);
  }

  // vr linear (split-K 8) -> partials -> rel[:,1424:1936]
  {
    GP g{}; g.A = ubuf; g.B = vr_w; g.C = pvr;
    g.M = 256; g.N = 512; g.K = 12544; g.kChunk = 1568;
    gemm_k<2><<<dim3(8,4,8), blk, 0, stream>>>(g);
    reduce_k<<<dim3(512), blk, 0, stream>>>(pvr, vr_b, rel, 8, 256*512, 512, 1936, 1424);
  }

  // lin: concat(s,o) @ lin_w^T -> z1
  {
    GP g{}; g.A = s_mat; g.A2 = o_mat; g.B = lin_w; g.bias = lin_b; g.C = z1;
    g.M = 256; g.N = 712; g.K = 1424; g.ldc = 712; g.coff = 0; g.kChunk = 1424;
    gemm_k<3><<<dim3(12,4,1), blk, 0, stream>>>(g);
  }

  // bilinear (split-K 24): A on the fly, B = bil_w rows -> partials -> bilbuf
  {
    GP g{}; g.A = s_mat; g.A2 = o_mat; g.B = bil_w; g.C = pbil;
    g.M = 256; g.N = 712; g.K = KBIL; g.kChunk = 21136;
    gemm_k<7><<<dim3(12,4,24), blk, 0, stream>>>(g);
    reduce_k<<<dim3(712), blk, 0, stream>>>(pbil, bil_b, bilbuf, 24, 256*712, 712, 712, 0);
  }

  // proj: relu(concat(z1,bil)) @ proj_w^T -> rel[:,0:1424]
  {
    GP g{}; g.A = z1; g.A2 = bilbuf; g.B = proj_w; g.bias = proj_b; g.C = rel;
    g.M = 256; g.N = 1424; g.K = 1424; g.ldc = 1936; g.coff = 0; g.kChunk = 1424;
    gemm_k<4><<<dim3(23,4,1), blk, 0, stream>>>(g);
  }

  // segments, memory zero + mask, scatter, pooled max
  seg_k<<<dim3(1), blk, 0, stream>>>(im_idx, counts, starts, pos);
  zeromask_k<<<dim3((SZ_MEM + SZ_MASK + 255)/256), blk, 0, stream>>>(out, counts);
  scatter_k<<<dim3(256), blk, 0, stream>>>(rel, pos, im_idx, out);
  pooled_k<<<dim3(8,16), blk, 0, stream>>>(rel, starts, counts, out);

  // act = sigmoid(pooled @ ac_w^T + ac_b)
  {
    GP g{}; g.A = out + OFF_POOLED; g.B = ac_w; g.bias = ac_b; g.C = out + OFF_ACT;
    g.M = 16; g.N = 157; g.K = 1936; g.ldc = 157; g.coff = 0; g.kChunk = 1936;
    gemm_k<8><<<dim3(3,1,1), blk, 0, stream>>>(g);
  }
}

// Round 3
// 4376.340 us; speedup vs baseline: 1.7335x; 1.7335x over previous
//
#include <hip/hip_runtime.h>
#include <math.h>

#define DEV __device__ __forceinline__

// ---- problem constants ----
#define PP    256          // pairs
#define BIMG  16
#define HB    712          // bilinear dim
#define KBIL  (712*712)    // 506944
#define KSTEPS (KBIL/32)   // 15842
#define DRELC 1936
#define BILSPLIT 24
#define BILCH   661        // ceil(15842/24)

// ---- d_out layout (floats) ----
#define SZ_ACT    (16*157)
#define OFF_ACT   0
#define OFF_POOLED (SZ_ACT)
#define SZ_POOLED (16*1936)
#define OFF_MEM   (OFF_POOLED + SZ_POOLED)
#define SZ_MEM    (24*16*1936)
#define OFF_MASK  (OFF_MEM + SZ_MEM)
#define SZ_MASK   (16*24)

// ---- ws layout (floats) ----
#define OFF_S     0
#define OFF_O     (OFF_S + 256*712)
#define OFF_Z1    (OFF_O + 256*712)
#define OFF_BIL   (OFF_Z1 + 256*712)
#define OFF_REL   (OFF_BIL + 256*712)
#define OFF_UBUF  (OFF_REL + 256*1936)
#define OFF_XP    (OFF_UBUF + 12544*256)
#define OFF_SHARED (OFF_XP + 256*128*49)
#define OFF_X1    OFF_SHARED                       // 256*128*196 floats
#define OFF_PVR   OFF_SHARED                       // 8*256*512
#define OFF_PBIL  (OFF_PVR + 8*256*512)            // 24*256*712
#define SZ_SHARED (256*128*196)                    // max(x1, pvr+pbil)
#define OFF_INTS  (OFF_SHARED + SZ_SHARED)

typedef __bf16 bf16x8 __attribute__((ext_vector_type(8)));
typedef float  f32x4  __attribute__((ext_vector_type(4)));

// ============================================================
// Bilinear via bf16-split MFMA.
// C[n][c] = sum_k A[n,k]*W[c,k], A[n,k]=s[n,k/712]*o[n,k%712].
// 3-term split: (a_hi+a_lo)(w_hi+w_lo) ~ ahi*whi + ahi*wlo + alo*whi.
// One block: 256 rows x 64 cols, split-K over blockIdx.y (24 chunks).
// W staged to LDS as hi/lo bf16, row stride 72 elems (144 B) for
// conflict-free ds_read_b128 / ds_write_b128.
// ============================================================
__global__ __launch_bounds__(256) void bil_mfma_k(
    const float* __restrict__ s, const float* __restrict__ o,
    const float* __restrict__ W, float* __restrict__ part) {
  __shared__ __align__(16) __bf16 Wsh[2][2][64*72];

  const int tid = threadIdx.x;
  const int C0 = blockIdx.x * 64;
  const int z0 = blockIdx.y * BILCH;
  const int zEnd = min(KSTEPS, z0 + BILCH);

  // staging role: thread -> (row 0..63, k-offset {0,8,16,24})
  const int srow = tid >> 2;
  const int koff = (tid & 3) * 8;
  const int sc = C0 + srow;
  const float* wbase = (sc < 712) ? (W + (size_t)sc * KBIL + koff) : (const float*)0;

  // compute role
  const int wv = tid >> 6, lane = tid & 63;
  const int lr = lane & 15, lg = lane >> 4;

  f32x4 acc[4][4];
  #pragma unroll
  for (int a = 0; a < 4; a++)
    #pragma unroll
    for (int b = 0; b < 4; b++) { acc[a][b][0]=0.f; acc[a][b][1]=0.f; acc[a][b][2]=0.f; acc[a][b][3]=0.f; }

  auto stage_load = [&](int z, float4& va, float4& vb) {
    if (wbase) {
      const float* p = wbase + (size_t)z * 32;
      va = *(const float4*)p;
      vb = *(const float4*)(p + 4);
    } else {
      va = make_float4(0.f,0.f,0.f,0.f);
      vb = make_float4(0.f,0.f,0.f,0.f);
    }
  };
  auto stage_write = [&](int buf, const float4& va, const float4& vb) {
    float t[8] = {va.x, va.y, va.z, va.w, vb.x, vb.y, vb.z, vb.w};
    bf16x8 hi, lo;
    #pragma unroll
    for (int i = 0; i < 8; i++) {
      float p = t[i];
      __bf16 h = (__bf16)p;
      hi[i] = h;
      lo[i] = (__bf16)(p - (float)h);
    }
    *(bf16x8*)&Wsh[buf][0][srow*72 + koff] = hi;
    *(bf16x8*)&Wsh[buf][1][srow*72 + koff] = lo;
  };

  { float4 va, vb; stage_load(z0, va, vb); stage_write(0, va, vb); }
  __syncthreads();

  for (int z = z0; z < zEnd; ++z) {
    const int cur = (z - z0) & 1;
    float4 va, vb;
    const bool pf = (z + 1 < zEnd);
    if (pf) stage_load(z + 1, va, vb);     // issue early; consumed after MFMA

    // ---- A fragments (per-wave, in registers) ----
    const int kk = z * 32 + lg * 8;
    const unsigned h = (unsigned)kk / 712u;
    const int t = kk - (int)h * 712;
    bf16x8 ahi[4], alo[4];
    #pragma unroll
    for (int rf = 0; rf < 4; rf++) {
      const int n = wv * 64 + rf * 16 + lr;
      const float sv = s[n * 712 + (int)h];
      const float* orow = o + n * 712 + t;
      float4 o0 = *(const float4*)orow;
      float4 o1 = *(const float4*)(orow + 4);
      float pv[8] = {o0.x,o0.y,o0.z,o0.w,o1.x,o1.y,o1.z,o1.w};
      #pragma unroll
      for (int i = 0; i < 8; i++) {
        float p = sv * pv[i];
        __bf16 hh = (__bf16)p;
        ahi[rf][i] = hh;
        alo[rf][i] = (__bf16)(p - (float)hh);
      }
    }

    // ---- MFMA: 4 col-frags x 4 row-frags x 3 terms ----
    #pragma unroll
    for (int cf = 0; cf < 4; cf++) {
      bf16x8 bhi = *(bf16x8*)&Wsh[cur][0][(cf*16 + lr)*72 + lg*8];
      bf16x8 blo = *(bf16x8*)&Wsh[cur][1][(cf*16 + lr)*72 + lg*8];
      #pragma unroll
      for (int rf = 0; rf < 4; rf++) {
        acc[rf][cf] = __builtin_amdgcn_mfma_f32_16x16x32_bf16(ahi[rf], bhi, acc[rf][cf], 0, 0, 0);
        acc[rf][cf] = __builtin_amdgcn_mfma_f32_16x16x32_bf16(ahi[rf], blo, acc[rf][cf], 0, 0, 0);
        acc[rf][cf] = __builtin_amdgcn_mfma_f32_16x16x32_bf16(alo[rf], bhi, acc[rf][cf], 0, 0, 0);
      }
    }

    if (pf) stage_write(cur ^ 1, va, vb);  // write-late: HBM latency hidden under MFMA
    __syncthreads();
  }

  // ---- epilogue: partials [z][256][712] ----
  const int bz = blockIdx.y;
  #pragma unroll
  for (int rf = 0; rf < 4; rf++) {
    #pragma unroll
    for (int cf = 0; cf < 4; cf++) {
      const int c = C0 + cf*16 + lr;
      if (c >= 712) continue;
      #pragma unroll
      for (int i = 0; i < 4; i++) {
        const int n = wv*64 + rf*16 + lg*4 + i;   // D: row=(lane>>4)*4+i, col=lane&15
        part[((size_t)bz*256 + n)*712 + c] = acc[rf][cf][i];
      }
    }
  }
}

struct GP {
  const float* A; const float* A2; const float* B; const float* bias;
  float* C;
  const int* gidx; int goff;
  int M, N, K;
  int ldc, coff;
  int kChunk;
  const float* bn_g; const float* bn_b; const float* bn_m; const float* bn_v;
};

// modes:
// 0: A row-gathered via gidx (features)         epi: +bias -> C
// 2: plain A, B = vr_w gather (k = q*256+oc)    epi: partial C[z][M][N]
// 3: A = concat(s,o)                            epi: +bias -> C
// 4: A = relu(concat(z1,bil))                   epi: +bias -> C
// 5: A = union_feat gather [(n,q)][ic]          epi: +bias -> C
// 6: A = im2col(xp) 3x3 pad1                    epi: bn2(relu(+bias)) += C
// 8: plain A                                    epi: sigmoid(+bias) -> C

template<int MODE>
DEV float loadA(const GP& p, int r, int k) {
  if (MODE == 0) { int fr = p.gidx[2*r + p.goff]; return p.A[fr*2048 + k]; }
  if (MODE == 2 || MODE == 8) return p.A[r*p.K + k];
  if (MODE == 3) return (k < 712) ? p.A[r*712 + k] : p.A2[r*712 + (k-712)];
  if (MODE == 4) { float v = (k < 712) ? p.A[r*712 + k] : p.A2[r*712 + (k-712)];
                   return fmaxf(v, 0.f); }
  if (MODE == 5) { int n = r/49, q = r - n*49; return p.A[(n*1024 + k)*49 + q]; }
  if (MODE == 6) {
    int n = r/49, q = r - n*49; int py = q/7, px = q - py*7;
    int ic = k/9, k9 = k - ic*9; int dy = k9/3, dx = k9 - dy*3;
    int iy = py + dy - 1, ix = px + dx - 1;
    if ((unsigned)iy >= 7u || (unsigned)ix >= 7u) return 0.f;
    return p.A[(n*128 + ic)*49 + iy*7 + ix];
  }
  return 0.f;
}

template<int MODE>
DEV float loadB(const GP& p, int c, int k) {
  if (MODE == 2) { int q = k >> 8, oc = k & 255; return p.B[c*12544 + oc*49 + q]; }
  return p.B[c*p.K + k];
}

template<int MODE>
__global__ __launch_bounds__(256) void gemm_k(GP p) {
  __shared__ float As[16][68];
  __shared__ float Bs[16][68];
  const int tid = threadIdx.x;
  const int tx = tid & 15, ty = tid >> 4;
  const int col0 = blockIdx.x * 64, row0 = blockIdx.y * 64;
  const int kStart = blockIdx.z * p.kChunk;
  const int kEnd = min(p.K, kStart + p.kChunk);
  float acc[4][4] = {};

  for (int kb = kStart; kb < kEnd; kb += 16) {
    if (MODE == 5 || MODE == 6) {
      int r = tid & 63, kk0 = tid >> 6;
      #pragma unroll
      for (int i = 0; i < 4; i++) {
        int kk = kk0 + i*4;
        int gr = row0 + r, gk = kb + kk;
        float v = 0.f;
        if (gr < p.M && gk < kEnd) v = loadA<MODE>(p, gr, gk);
        As[kk][r] = v;
      }
    } else {
      int kk = tid & 15, r0 = tid >> 4;
      #pragma unroll
      for (int i = 0; i < 4; i++) {
        int r = r0 + i*16;
        int gr = row0 + r, gk = kb + kk;
        float v = 0.f;
        if (gr < p.M && gk < kEnd) v = loadA<MODE>(p, gr, gk);
        As[kk][r] = v;
      }
    }
    {
      int kk = tid & 15, c0 = tid >> 4;
      #pragma unroll
      for (int i = 0; i < 4; i++) {
        int c = c0 + i*16;
        int gc = col0 + c, gk = kb + kk;
        float v = 0.f;
        if (gc < p.N && gk < kEnd) v = loadB<MODE>(p, gc, gk);
        Bs[kk][c] = v;
      }
    }
    __syncthreads();
    #pragma unroll
    for (int kk = 0; kk < 16; kk++) {
      float a[4], b[4];
      #pragma unroll
      for (int j = 0; j < 4; j++) a[j] = As[kk][ty*4 + j];
      #pragma unroll
      for (int j = 0; j < 4; j++) b[j] = Bs[kk][tx*4 + j];
      #pragma unroll
      for (int i = 0; i < 4; i++)
        #pragma unroll
        for (int j = 0; j < 4; j++) acc[i][j] += a[i]*b[j];
    }
    __syncthreads();
  }

  #pragma unroll
  for (int i = 0; i < 4; i++) {
    int r = row0 + ty*4 + i;
    if (r >= p.M) continue;
    #pragma unroll
    for (int j = 0; j < 4; j++) {
      int c = col0 + tx*4 + j;
      if (c >= p.N) continue;
      float v = acc[i][j];
      if (MODE == 2) {
        p.C[(size_t)blockIdx.z * p.M * p.N + (size_t)r * p.N + c] = v;
      } else if (MODE == 6) {
        float sc = p.bn_g[c] / sqrtf(p.bn_v[c] + 1e-5f);
        float sh = p.bn_b[c] - p.bn_m[c]*sc;
        float t2 = fmaxf(v + p.bias[c], 0.f)*sc + sh;
        p.C[r*p.ldc + p.coff + c] += t2;
      } else if (MODE == 8) {
        float t2 = v + p.bias[c];
        p.C[r*p.ldc + p.coff + c] = 1.f/(1.f + expf(-t2));
      } else {
        p.C[r*p.ldc + p.coff + c] = v + p.bias[c];
      }
    }
  }
}

__global__ __launch_bounds__(256) void reduce_k(const float* __restrict__ part,
    const float* __restrict__ bias, float* __restrict__ out,
    int S, int MN, int N, int ldc, int coff) {
  int i = blockIdx.x*256 + threadIdx.x;
  if (i >= MN) return;
  float s = 0.f;
  for (int z = 0; z < S; z++) s += part[(size_t)z*MN + i];
  int r = i / N, c = i - r*N;
  out[r*ldc + coff + c] = s + bias[c];
}

__global__ __launch_bounds__(256) void emb_k(const int* __restrict__ pi,
    const int* __restrict__ labels, const float* __restrict__ e1,
    const float* __restrict__ e2, float* __restrict__ s, float* __restrict__ o) {
  int i = blockIdx.x*256 + threadIdx.x;
  if (i >= 2*256*200) return;
  int which = i / (256*200); int rest = i - which*(256*200);
  int n = rest / 200; int j = rest - n*200;
  int lab = labels[pi[2*n + which]];
  float v = which ? e2[lab*200 + j] : e1[lab*200 + j];
  (which ? o : s)[n*712 + 512 + j] = v;
}

__global__ __launch_bounds__(256) void conv1_k(const float* __restrict__ in,
    const float* __restrict__ w, const float* __restrict__ bias,
    const float* __restrict__ g, const float* __restrict__ bt,
    const float* __restrict__ m, const float* __restrict__ vv,
    float* __restrict__ out) {
  int idx = blockIdx.x*256 + threadIdx.x;
  if (idx >= 256*128*14) return;
  int oy = idx % 14; int t = idx / 14; int c = t & 127; int n = t >> 7;
  float acc[14];
  float b0 = bias[c];
  #pragma unroll
  for (int ox = 0; ox < 14; ox++) acc[ox] = b0;
  for (int ci = 0; ci < 2; ci++) {
    #pragma unroll
    for (int ky = 0; ky < 7; ky++) {
      int iy = oy*2 - 3 + ky;
      if ((unsigned)iy >= 27u) continue;
      const float* ir = in + ((n*2 + ci)*27 + iy)*27;
      const float* wr = w + ((c*2 + ci)*7 + ky)*7;
      float iv[27];
      #pragma unroll
      for (int x = 0; x < 27; x++) iv[x] = ir[x];
      float wk[7];
      #pragma unroll
      for (int kx = 0; kx < 7; kx++) wk[kx] = wr[kx];
      #pragma unroll
      for (int kx = 0; kx < 7; kx++)
        #pragma unroll
        for (int ox = 0; ox < 14; ox++) {
          int ix = ox*2 - 3 + kx;
          if (ix >= 0 && ix < 27) acc[ox] += iv[ix]*wk[kx];
        }
    }
  }
  float sc = g[c] / sqrtf(vv[c] + 1e-5f);
  float sh = bt[c] - m[c]*sc;
  float* orow = out + ((n*128 + c)*14 + oy)*14;
  #pragma unroll
  for (int ox = 0; ox < 14; ox++) orow[ox] = fmaxf(acc[ox], 0.f)*sc + sh;
}

__global__ __launch_bounds__(256) void pool_k(const float* __restrict__ x1,
                                              float* __restrict__ xp) {
  int idx = blockIdx.x*256 + threadIdx.x;
  if (idx >= 256*128*49) return;
  int px = idx % 7; int t = idx / 7; int py = t % 7; t /= 7;
  int c = t & 127; int n = t >> 7;
  float mx = -INFINITY;
  for (int dy = 0; dy < 3; dy++) {
    int y = py*2 - 1 + dy;
    if ((unsigned)y >= 14u) continue;
    for (int dx = 0; dx < 3; dx++) {
      int x = px*2 - 1 + dx;
      if ((unsigned)x >= 14u) continue;
      mx = fmaxf(mx, x1[((n*128 + c)*14 + y)*14 + x]);
    }
  }
  xp[((n*128 + c)*7 + py)*7 + px] = mx;
}

__global__ __launch_bounds__(256) void seg_k(const int* __restrict__ im,
    int* __restrict__ counts, int* __restrict__ starts, int* __restrict__ pos) {
  __shared__ int c[16], s[16];
  int tid = threadIdx.x;
  if (tid < 16) c[tid] = 0;
  __syncthreads();
  atomicAdd(&c[im[tid]], 1);
  __syncthreads();
  if (tid == 0) { int run = 0; for (int b = 0; b < 16; b++) { s[b] = run; run += c[b]; } }
  __syncthreads();
  if (tid < 16) { counts[tid] = c[tid]; starts[tid] = s[tid]; }
  pos[tid] = tid - s[im[tid]];
}

__global__ __launch_bounds__(256) void zeromask_k(float* __restrict__ out,
                                                  const int* __restrict__ counts) {
  int i = blockIdx.x*256 + threadIdx.x;
  if (i < SZ_MEM) { out[OFF_MEM + i] = 0.f; return; }
  int j = i - SZ_MEM;
  if (j < SZ_MASK) {
    int b = j / 24, l = j - b*24;
    out[OFF_MASK + j] = (l >= counts[b]) ? 1.f : 0.f;
  }
}

__global__ __launch_bounds__(256) void scatter_k(const float* __restrict__ rel,
    const int* __restrict__ pos, const int* __restrict__ im, float* __restrict__ out) {
  int n = blockIdx.x;
  int l = pos[n], b = im[n];
  float* dst = out + OFF_MEM + ((size_t)l*16 + b)*1936;
  const float* src = rel + (size_t)n*1936;
  for (int d = threadIdx.x; d < 1936; d += 256) dst[d] = src[d];
}

__global__ __launch_bounds__(256) void pooled_k(const float* __restrict__ rel,
    const int* __restrict__ starts, const int* __restrict__ counts,
    float* __restrict__ out) {
  int b = blockIdx.y;
  int d = blockIdx.x*256 + threadIdx.x;
  if (d >= 1936) return;
  int st = starts[b], ct = counts[b];
  float mx = -INFINITY;
  for (int i = 0; i < ct; i++) mx = fmaxf(mx, rel[(size_t)(st + i)*1936 + d]);
  out[OFF_POOLED + b*1936 + d] = mx;
}

extern "C" void kernel_launch(void* const* d_in, const int* in_sizes, int n_in,
                              void* d_out, int out_size, void* d_ws, size_t ws_size,
                              hipStream_t stream) {
  const float* features   = (const float*)d_in[0];
  const int*   pair_idx   = (const int*)d_in[1];
  const int*   im_idx     = (const int*)d_in[2];
  const int*   labels     = (const int*)d_in[3];
  const float* union_feat = (const float*)d_in[4];
  const float* spatial    = (const float*)d_in[5];
  const float* w_union    = (const float*)d_in[6];
  const float* b_union    = (const float*)d_in[7];
  const float* conv1_w    = (const float*)d_in[8];
  const float* conv1_b    = (const float*)d_in[9];
  const float* bn1_g      = (const float*)d_in[10];
  const float* bn1_b      = (const float*)d_in[11];
  const float* bn1_m      = (const float*)d_in[12];
  const float* bn1_v      = (const float*)d_in[13];
  const float* conv2_w    = (const float*)d_in[14];
  const float* conv2_b    = (const float*)d_in[15];
  const float* bn2_g      = (const float*)d_in[16];
  const float* bn2_b      = (const float*)d_in[17];
  const float* bn2_m      = (const float*)d_in[18];
  const float* bn2_v      = (const float*)d_in[19];
  const float* subj_w     = (const float*)d_in[20];
  const float* subj_b     = (const float*)d_in[21];
  const float* obj_w      = (const float*)d_in[22];
  const float* obj_b      = (const float*)d_in[23];
  const float* vr_w       = (const float*)d_in[24];
  const float* vr_b       = (const float*)d_in[25];
  const float* emb1       = (const float*)d_in[26];
  const float* emb2       = (const float*)d_in[27];
  const float* bil_w      = (const float*)d_in[28];
  const float* bil_b      = (const float*)d_in[29];
  const float* lin_w      = (const float*)d_in[30];
  const float* lin_b      = (const float*)d_in[31];
  const float* proj_w     = (const float*)d_in[32];
  const float* proj_b     = (const float*)d_in[33];
  const float* ac_w       = (const float*)d_in[34];
  const float* ac_b       = (const float*)d_in[35];

  float* ws = (float*)d_ws;
  float* s_mat  = ws + OFF_S;
  float* o_mat  = ws + OFF_O;
  float* z1     = ws + OFF_Z1;
  float* bilbuf = ws + OFF_BIL;
  float* rel    = ws + OFF_REL;
  float* ubuf   = ws + OFF_UBUF;
  float* x1     = ws + OFF_X1;
  float* xp     = ws + OFF_XP;
  float* pvr    = ws + OFF_PVR;
  float* pbil   = ws + OFF_PBIL;
  int*   ints   = (int*)(ws + OFF_INTS);
  int* counts = ints; int* starts = ints + 16; int* pos = ints + 32;
  float* out = (float*)d_out;

  dim3 blk(256);

  // subj / obj linears (gathered rows of features) -> s_mat/o_mat cols [0,512)
  {
    GP g{}; g.A = features; g.B = subj_w; g.bias = subj_b; g.C = s_mat;
    g.gidx = pair_idx; g.goff = 0; g.M = 256; g.N = 512; g.K = 2048;
    g.ldc = 712; g.coff = 0; g.kChunk = 2048;
    gemm_k<0><<<dim3(8,4,1), blk, 0, stream>>>(g);
    g.goff = 1; g.B = obj_w; g.bias = obj_b; g.C = o_mat;
    gemm_k<0><<<dim3(8,4,1), blk, 0, stream>>>(g);
  }
  // embedding concat -> cols [512,712)
  emb_k<<<dim3(400), blk, 0, stream>>>(pair_idx, labels, emb1, emb2, s_mat, o_mat);

  // union 1x1 conv as GEMM -> ubuf[(n,q)][oc]
  {
    GP g{}; g.A = union_feat; g.B = w_union; g.bias = b_union; g.C = ubuf;
    g.M = 12544; g.N = 256; g.K = 1024; g.ldc = 256; g.coff = 0; g.kChunk = 1024;
    gemm_k<5><<<dim3(4,196,1), blk, 0, stream>>>(g);
  }

  // conv1 + relu + bn1 -> x1 ; maxpool -> xp
  conv1_k<<<dim3(1792), blk, 0, stream>>>(spatial, conv1_w, conv1_b,
                                          bn1_g, bn1_b, bn1_m, bn1_v, x1);
  pool_k<<<dim3(6272), blk, 0, stream>>>(x1, xp);

  // conv2 (implicit GEMM) + relu + bn2, accumulated into ubuf
  {
    GP g{}; g.A = xp; g.B = conv2_w; g.bias = conv2_b; g.C = ubuf;
    g.M = 12544; g.N = 256; g.K = 1152; g.ldc = 256; g.coff = 0; g.kChunk = 1152;
    g.bn_g = bn2_g; g.bn_b = bn2_b; g.bn_m = bn2_m; g.bn_v = bn2_v;
    gemm_k<6><<<dim3(4,196,1), blk, 0, stream>>>(g);
  }

  // vr linear (split-K 8) -> partials -> rel[:,1424:1936]
  {
    GP g{}; g.A = ubuf; g.B = vr_w; g.C = pvr;
    g.M = 256; g.N = 512; g.K = 12544; g.kChunk = 1568;
    gemm_k<2><<<dim3(8,4,8), blk, 0, stream>>>(g);
    reduce_k<<<dim3(512), blk, 0, stream>>>(pvr, vr_b, rel, 8, 256*512, 512, 1936, 1424);
  }

  // lin: concat(s,o) @ lin_w^T -> z1
  {
    GP g{}; g.A = s_mat; g.A2 = o_mat; g.B = lin_w; g.bias = lin_b; g.C = z1;
    g.M = 256; g.N = 712; g.K = 1424; g.ldc = 712; g.coff = 0; g.kChunk = 1424;
    gemm_k<3><<<dim3(12,4,1), blk, 0, stream>>>(g);
  }

  // bilinear: bf16-split MFMA, split-K 24 -> partials -> bilbuf
  bil_mfma_k<<<dim3(12, BILSPLIT), blk, 0, stream>>>(s_mat, o_mat, bil_w, pbil);
  reduce_k<<<dim3(712), blk, 0, stream>>>(pbil, bil_b, bilbuf, BILSPLIT, 256*712, 712, 712, 0);

  // proj: relu(concat(z1,bil)) @ proj_w^T -> rel[:,0:1424]
  {
    GP g{}; g.A = z1; g.A2 = bilbuf; g.B = proj_w; g.bias = proj_b; g.C = rel;
    g.M = 256; g.N = 1424; g.K = 1424; g.ldc = 1936; g.coff = 0; g.kChunk = 1424;
    gemm_k<4><<<dim3(23,4,1), blk, 0, stream>>>(g);
  }

  // segments, memory zero + mask, scatter, pooled max
  seg_k<<<dim3(1), blk, 0, stream>>>(im_idx, counts, starts, pos);
  zeromask_k<<<dim3((SZ_MEM + SZ_MASK + 255)/256), blk, 0, stream>>>(out, counts);
  scatter_k<<<dim3(256), blk, 0, stream>>>(rel, pos, im_idx, out);
  pooled_k<<<dim3(8,16), blk, 0, stream>>>(rel, starts, counts, out);

  // act = sigmoid(pooled @ ac_w^T + ac_b)
  {
    GP g{}; g.A = out + OFF_POOLED; g.B = ac_w; g.bias = ac_b; g.C = out + OFF_ACT;
    g.M = 16; g.N = 157; g.K = 1936; g.ldc = 157; g.coff = 0; g.kChunk = 1936;
    gemm_k<8><<<dim3(3,1,1), blk, 0, stream>>>(g);
  }
}

// Round 4
// 3978.137 us; speedup vs baseline: 1.9071x; 1.1001x over previous
//
#include <hip/hip_runtime.h>
#include <math.h>

#define DEV __device__ __forceinline__

// ---- problem constants ----
#define PP    256          // pairs
#define BIMG  16
#define HB    712          // bilinear dim
#define KBIL  (712*712)    // 506944
#define KSTEPS (KBIL/32)   // 15842
#define DRELC 1936
#define BILSPLIT 48
#define BILCH   331        // ceil(15842/48)

// ---- d_out layout (floats) ----
#define SZ_ACT    (16*157)
#define OFF_ACT   0
#define OFF_POOLED (SZ_ACT)
#define SZ_POOLED (16*1936)
#define OFF_MEM   (OFF_POOLED + SZ_POOLED)
#define SZ_MEM    (24*16*1936)
#define OFF_MASK  (OFF_MEM + SZ_MEM)
#define SZ_MASK   (16*24)

// ---- ws layout (floats) ----
#define OFF_S     0
#define OFF_O     (OFF_S + 256*712)
#define OFF_Z1    (OFF_O + 256*712)
#define OFF_BIL   (OFF_Z1 + 256*712)
#define OFF_REL   (OFF_BIL + 256*712)
#define OFF_UBUF  (OFF_REL + 256*1936)
#define OFF_XP    (OFF_UBUF + 12544*256)
#define OFF_SHARED (OFF_XP + 256*128*49)
#define OFF_X1    OFF_SHARED                       // 256*128*196 floats
#define OFF_PVR   OFF_SHARED                       // 8*256*512
// pbil (48*256*712 = 8.75M floats) aliases ubuf+xp+shared, all dead
// by the time the bilinear runs. Extends to 9.97M < OFF_INTS (12.46M).
#define OFF_PBIL  OFF_UBUF
#define SZ_SHARED (256*128*196)                    // max(x1, pvr)
#define OFF_INTS  (OFF_SHARED + SZ_SHARED)

typedef __bf16 bf16x4 __attribute__((ext_vector_type(4)));
typedef __bf16 bf16x8 __attribute__((ext_vector_type(8)));
typedef float  f32x4  __attribute__((ext_vector_type(4)));

// ============================================================
// Bilinear via bf16-split MFMA.
// C[n][c] = sum_k A[n,k]*W[c,k], A[n,k]=s[n,k/712]*o[n,k%712].
// 3-term split: ahi*whi + ahi*wlo + alo*whi  (rel err ~2^-16/term).
// Block: 256 rows x 64 cols, 8 waves (each 2 row-frags of 16),
// split-K over blockIdx.y (48 chunks) -> 576 blocks, ~18 waves/CU.
// W staged to LDS hi/lo bf16, row stride 72 elems (144 B).
// ============================================================
__global__ __launch_bounds__(512) void bil_mfma_k(
    const float* __restrict__ s, const float* __restrict__ o,
    const float* __restrict__ W, float* __restrict__ part) {
  __shared__ __align__(16) __bf16 Wsh[2][2][64*72];

  const int tid = threadIdx.x;
  const int C0 = blockIdx.x * 64;
  const int z0 = blockIdx.y * BILCH;
  const int zEnd = min(KSTEPS, z0 + BILCH);

  // staging role: 64 rows x 32 floats; 8 threads/row, float4 each
  const int srow = tid >> 3;
  const int koff = (tid & 7) * 4;
  const int sc = C0 + srow;
  const float* wbase = (sc < 712) ? (W + (size_t)sc * KBIL + koff) : (const float*)0;

  // compute role
  const int wv = tid >> 6, lane = tid & 63;
  const int lr = lane & 15, lg = lane >> 4;

  f32x4 acc[2][4];
  #pragma unroll
  for (int a = 0; a < 2; a++)
    #pragma unroll
    for (int b = 0; b < 4; b++) { acc[a][b][0]=0.f; acc[a][b][1]=0.f; acc[a][b][2]=0.f; acc[a][b][3]=0.f; }

  auto stage_load = [&](int z, float4& va) {
    va = wbase ? *(const float4*)(wbase + (size_t)z * 32) : make_float4(0.f,0.f,0.f,0.f);
  };
  auto stage_write = [&](int buf, const float4& va) {
    float t[4] = {va.x, va.y, va.z, va.w};
    bf16x4 hi, lo;
    #pragma unroll
    for (int i = 0; i < 4; i++) {
      float p = t[i];
      __bf16 h = (__bf16)p;
      hi[i] = h;
      lo[i] = (__bf16)(p - (float)h);
    }
    *(bf16x4*)&Wsh[buf][0][srow*72 + koff] = hi;
    *(bf16x4*)&Wsh[buf][1][srow*72 + koff] = lo;
  };

  { float4 va; stage_load(z0, va); stage_write(0, va); }
  __syncthreads();

  for (int z = z0; z < zEnd; ++z) {
    const int cur = (z - z0) & 1;
    float4 va;
    const bool pf = (z + 1 < zEnd);
    if (pf) stage_load(z + 1, va);         // issue early; consumed after MFMA

    // ---- A fragments (per-wave, in registers) ----
    const int kk = z * 32 + lg * 8;
    const unsigned h = (unsigned)kk / 712u;
    const int t = kk - (int)h * 712;
    bf16x8 ahi[2], alo[2];
    #pragma unroll
    for (int rf = 0; rf < 2; rf++) {
      const int n = wv * 32 + rf * 16 + lr;
      const float sv = s[n * 712 + (int)h];
      const float* orow = o + n * 712 + t;
      float4 o0 = *(const float4*)orow;
      float4 o1 = *(const float4*)(orow + 4);
      float pv[8] = {o0.x,o0.y,o0.z,o0.w,o1.x,o1.y,o1.z,o1.w};
      #pragma unroll
      for (int i = 0; i < 8; i++) {
        float p = sv * pv[i];
        __bf16 hh = (__bf16)p;
        ahi[rf][i] = hh;
        alo[rf][i] = (__bf16)(p - (float)hh);
      }
    }

    // ---- MFMA: 4 col-frags x 2 row-frags x 3 terms ----
    #pragma unroll
    for (int cf = 0; cf < 4; cf++) {
      bf16x8 bhi = *(bf16x8*)&Wsh[cur][0][(cf*16 + lr)*72 + lg*8];
      bf16x8 blo = *(bf16x8*)&Wsh[cur][1][(cf*16 + lr)*72 + lg*8];
      #pragma unroll
      for (int rf = 0; rf < 2; rf++) {
        acc[rf][cf] = __builtin_amdgcn_mfma_f32_16x16x32_bf16(ahi[rf], bhi, acc[rf][cf], 0, 0, 0);
        acc[rf][cf] = __builtin_amdgcn_mfma_f32_16x16x32_bf16(ahi[rf], blo, acc[rf][cf], 0, 0, 0);
        acc[rf][cf] = __builtin_amdgcn_mfma_f32_16x16x32_bf16(alo[rf], bhi, acc[rf][cf], 0, 0, 0);
      }
    }

    if (pf) stage_write(cur ^ 1, va);      // write-late: HBM latency hidden under MFMA
    __syncthreads();
  }

  // ---- epilogue: partials [z][256][712] ----
  const int bz = blockIdx.y;
  #pragma unroll
  for (int rf = 0; rf < 2; rf++) {
    #pragma unroll
    for (int cf = 0; cf < 4; cf++) {
      const int c = C0 + cf*16 + lr;
      if (c >= 712) continue;
      #pragma unroll
      for (int i = 0; i < 4; i++) {
        const int n = wv*32 + rf*16 + lg*4 + i;   // D: row=(lane>>4)*4+i, col=lane&15
        part[((size_t)bz*256 + n)*712 + c] = acc[rf][cf][i];
      }
    }
  }
}

struct GP {
  const float* A; const float* A2; const float* B; const float* bias;
  float* C;
  const int* gidx; int goff;
  int M, N, K;
  int ldc, coff;
  int kChunk;
  const float* bn_g; const float* bn_b; const float* bn_m; const float* bn_v;
};

// modes:
// 0: A row-gathered via gidx (features)         epi: +bias -> C
// 2: plain A, B = vr_w gather (k = q*256+oc)    epi: partial C[z][M][N]
// 3: A = concat(s,o)                            epi: +bias -> C
// 4: A = relu(concat(z1,bil))                   epi: +bias -> C
// 5: A = union_feat gather [(n,q)][ic]          epi: +bias -> C
// 6: A = im2col(xp) 3x3 pad1                    epi: bn2(relu(+bias)) += C
// 8: plain A                                    epi: sigmoid(+bias) -> C

template<int MODE>
DEV float loadA(const GP& p, int r, int k) {
  if (MODE == 0) { int fr = p.gidx[2*r + p.goff]; return p.A[fr*2048 + k]; }
  if (MODE == 2 || MODE == 8) return p.A[r*p.K + k];
  if (MODE == 3) return (k < 712) ? p.A[r*712 + k] : p.A2[r*712 + (k-712)];
  if (MODE == 4) { float v = (k < 712) ? p.A[r*712 + k] : p.A2[r*712 + (k-712)];
                   return fmaxf(v, 0.f); }
  if (MODE == 5) { int n = r/49, q = r - n*49; return p.A[(n*1024 + k)*49 + q]; }
  if (MODE == 6) {
    int n = r/49, q = r - n*49; int py = q/7, px = q - py*7;
    int ic = k/9, k9 = k - ic*9; int dy = k9/3, dx = k9 - dy*3;
    int iy = py + dy - 1, ix = px + dx - 1;
    if ((unsigned)iy >= 7u || (unsigned)ix >= 7u) return 0.f;
    return p.A[(n*128 + ic)*49 + iy*7 + ix];
  }
  return 0.f;
}

template<int MODE>
DEV float loadB(const GP& p, int c, int k) {
  if (MODE == 2) { int q = k >> 8, oc = k & 255; return p.B[c*12544 + oc*49 + q]; }
  return p.B[c*p.K + k];
}

template<int MODE>
__global__ __launch_bounds__(256) void gemm_k(GP p) {
  __shared__ float As[16][68];
  __shared__ float Bs[16][68];
  const int tid = threadIdx.x;
  const int tx = tid & 15, ty = tid >> 4;
  const int col0 = blockIdx.x * 64, row0 = blockIdx.y * 64;
  const int kStart = blockIdx.z * p.kChunk;
  const int kEnd = min(p.K, kStart + p.kChunk);
  float acc[4][4] = {};

  for (int kb = kStart; kb < kEnd; kb += 16) {
    if (MODE == 5 || MODE == 6) {
      int r = tid & 63, kk0 = tid >> 6;
      #pragma unroll
      for (int i = 0; i < 4; i++) {
        int kk = kk0 + i*4;
        int gr = row0 + r, gk = kb + kk;
        float v = 0.f;
        if (gr < p.M && gk < kEnd) v = loadA<MODE>(p, gr, gk);
        As[kk][r] = v;
      }
    } else {
      int kk = tid & 15, r0 = tid >> 4;
      #pragma unroll
      for (int i = 0; i < 4; i++) {
        int r = r0 + i*16;
        int gr = row0 + r, gk = kb + kk;
        float v = 0.f;
        if (gr < p.M && gk < kEnd) v = loadA<MODE>(p, gr, gk);
        As[kk][r] = v;
      }
    }
    {
      int kk = tid & 15, c0 = tid >> 4;
      #pragma unroll
      for (int i = 0; i < 4; i++) {
        int c = c0 + i*16;
        int gc = col0 + c, gk = kb + kk;
        float v = 0.f;
        if (gc < p.N && gk < kEnd) v = loadB<MODE>(p, gc, gk);
        Bs[kk][c] = v;
      }
    }
    __syncthreads();
    #pragma unroll
    for (int kk = 0; kk < 16; kk++) {
      float a[4], b[4];
      #pragma unroll
      for (int j = 0; j < 4; j++) a[j] = As[kk][ty*4 + j];
      #pragma unroll
      for (int j = 0; j < 4; j++) b[j] = Bs[kk][tx*4 + j];
      #pragma unroll
      for (int i = 0; i < 4; i++)
        #pragma unroll
        for (int j = 0; j < 4; j++) acc[i][j] += a[i]*b[j];
    }
    __syncthreads();
  }

  #pragma unroll
  for (int i = 0; i < 4; i++) {
    int r = row0 + ty*4 + i;
    if (r >= p.M) continue;
    #pragma unroll
    for (int j = 0; j < 4; j++) {
      int c = col0 + tx*4 + j;
      if (c >= p.N) continue;
      float v = acc[i][j];
      if (MODE == 2) {
        p.C[(size_t)blockIdx.z * p.M * p.N + (size_t)r * p.N + c] = v;
      } else if (MODE == 6) {
        float sc = p.bn_g[c] / sqrtf(p.bn_v[c] + 1e-5f);
        float sh = p.bn_b[c] - p.bn_m[c]*sc;
        float t2 = fmaxf(v + p.bias[c], 0.f)*sc + sh;
        p.C[r*p.ldc + p.coff + c] += t2;
      } else if (MODE == 8) {
        float t2 = v + p.bias[c];
        p.C[r*p.ldc + p.coff + c] = 1.f/(1.f + expf(-t2));
      } else {
        p.C[r*p.ldc + p.coff + c] = v + p.bias[c];
      }
    }
  }
}

__global__ __launch_bounds__(256) void reduce_k(const float* __restrict__ part,
    const float* __restrict__ bias, float* __restrict__ out,
    int S, int MN, int N, int ldc, int coff) {
  int i = blockIdx.x*256 + threadIdx.x;
  if (i >= MN) return;
  float s = 0.f;
  for (int z = 0; z < S; z++) s += part[(size_t)z*MN + i];
  int r = i / N, c = i - r*N;
  out[r*ldc + coff + c] = s + bias[c];
}

__global__ __launch_bounds__(256) void emb_k(const int* __restrict__ pi,
    const int* __restrict__ labels, const float* __restrict__ e1,
    const float* __restrict__ e2, float* __restrict__ s, float* __restrict__ o) {
  int i = blockIdx.x*256 + threadIdx.x;
  if (i >= 2*256*200) return;
  int which = i / (256*200); int rest = i - which*(256*200);
  int n = rest / 200; int j = rest - n*200;
  int lab = labels[pi[2*n + which]];
  float v = which ? e2[lab*200 + j] : e1[lab*200 + j];
  (which ? o : s)[n*712 + 512 + j] = v;
}

__global__ __launch_bounds__(256) void conv1_k(const float* __restrict__ in,
    const float* __restrict__ w, const float* __restrict__ bias,
    const float* __restrict__ g, const float* __restrict__ bt,
    const float* __restrict__ m, const float* __restrict__ vv,
    float* __restrict__ out) {
  int idx = blockIdx.x*256 + threadIdx.x;
  if (idx >= 256*128*14) return;
  int oy = idx % 14; int t = idx / 14; int c = t & 127; int n = t >> 7;
  float acc[14];
  float b0 = bias[c];
  #pragma unroll
  for (int ox = 0; ox < 14; ox++) acc[ox] = b0;
  for (int ci = 0; ci < 2; ci++) {
    #pragma unroll
    for (int ky = 0; ky < 7; ky++) {
      int iy = oy*2 - 3 + ky;
      if ((unsigned)iy >= 27u) continue;
      const float* ir = in + ((n*2 + ci)*27 + iy)*27;
      const float* wr = w + ((c*2 + ci)*7 + ky)*7;
      float iv[27];
      #pragma unroll
      for (int x = 0; x < 27; x++) iv[x] = ir[x];
      float wk[7];
      #pragma unroll
      for (int kx = 0; kx < 7; kx++) wk[kx] = wr[kx];
      #pragma unroll
      for (int kx = 0; kx < 7; kx++)
        #pragma unroll
        for (int ox = 0; ox < 14; ox++) {
          int ix = ox*2 - 3 + kx;
          if (ix >= 0 && ix < 27) acc[ox] += iv[ix]*wk[kx];
        }
    }
  }
  float sc = g[c] / sqrtf(vv[c] + 1e-5f);
  float sh = bt[c] - m[c]*sc;
  float* orow = out + ((n*128 + c)*14 + oy)*14;
  #pragma unroll
  for (int ox = 0; ox < 14; ox++) orow[ox] = fmaxf(acc[ox], 0.f)*sc + sh;
}

__global__ __launch_bounds__(256) void pool_k(const float* __restrict__ x1,
                                              float* __restrict__ xp) {
  int idx = blockIdx.x*256 + threadIdx.x;
  if (idx >= 256*128*49) return;
  int px = idx % 7; int t = idx / 7; int py = t % 7; t /= 7;
  int c = t & 127; int n = t >> 7;
  float mx = -INFINITY;
  for (int dy = 0; dy < 3; dy++) {
    int y = py*2 - 1 + dy;
    if ((unsigned)y >= 14u) continue;
    for (int dx = 0; dx < 3; dx++) {
      int x = px*2 - 1 + dx;
      if ((unsigned)x >= 14u) continue;
      mx = fmaxf(mx, x1[((n*128 + c)*14 + y)*14 + x]);
    }
  }
  xp[((n*128 + c)*7 + py)*7 + px] = mx;
}

__global__ __launch_bounds__(256) void seg_k(const int* __restrict__ im,
    int* __restrict__ counts, int* __restrict__ starts, int* __restrict__ pos) {
  __shared__ int c[16], s[16];
  int tid = threadIdx.x;
  if (tid < 16) c[tid] = 0;
  __syncthreads();
  atomicAdd(&c[im[tid]], 1);
  __syncthreads();
  if (tid == 0) { int run = 0; for (int b = 0; b < 16; b++) { s[b] = run; run += c[b]; } }
  __syncthreads();
  if (tid < 16) { counts[tid] = c[tid]; starts[tid] = s[tid]; }
  pos[tid] = tid - s[im[tid]];
}

__global__ __launch_bounds__(256) void zeromask_k(float* __restrict__ out,
                                                  const int* __restrict__ counts) {
  int i = blockIdx.x*256 + threadIdx.x;
  if (i < SZ_MEM) { out[OFF_MEM + i] = 0.f; return; }
  int j = i - SZ_MEM;
  if (j < SZ_MASK) {
    int b = j / 24, l = j - b*24;
    out[OFF_MASK + j] = (l >= counts[b]) ? 1.f : 0.f;
  }
}

__global__ __launch_bounds__(256) void scatter_k(const float* __restrict__ rel,
    const int* __restrict__ pos, const int* __restrict__ im, float* __restrict__ out) {
  int n = blockIdx.x;
  int l = pos[n], b = im[n];
  float* dst = out + OFF_MEM + ((size_t)l*16 + b)*1936;
  const float* src = rel + (size_t)n*1936;
  for (int d = threadIdx.x; d < 1936; d += 256) dst[d] = src[d];
}

__global__ __launch_bounds__(256) void pooled_k(const float* __restrict__ rel,
    const int* __restrict__ starts, const int* __restrict__ counts,
    float* __restrict__ out) {
  int b = blockIdx.y;
  int d = blockIdx.x*256 + threadIdx.x;
  if (d >= 1936) return;
  int st = starts[b], ct = counts[b];
  float mx = -INFINITY;
  for (int i = 0; i < ct; i++) mx = fmaxf(mx, rel[(size_t)(st + i)*1936 + d]);
  out[OFF_POOLED + b*1936 + d] = mx;
}

extern "C" void kernel_launch(void* const* d_in, const int* in_sizes, int n_in,
                              void* d_out, int out_size, void* d_ws, size_t ws_size,
                              hipStream_t stream) {
  const float* features   = (const float*)d_in[0];
  const int*   pair_idx   = (const int*)d_in[1];
  const int*   im_idx     = (const int*)d_in[2];
  const int*   labels     = (const int*)d_in[3];
  const float* union_feat = (const float*)d_in[4];
  const float* spatial    = (const float*)d_in[5];
  const float* w_union    = (const float*)d_in[6];
  const float* b_union    = (const float*)d_in[7];
  const float* conv1_w    = (const float*)d_in[8];
  const float* conv1_b    = (const float*)d_in[9];
  const float* bn1_g      = (const float*)d_in[10];
  const float* bn1_b      = (const float*)d_in[11];
  const float* bn1_m      = (const float*)d_in[12];
  const float* bn1_v      = (const float*)d_in[13];
  const float* conv2_w    = (const float*)d_in[14];
  const float* conv2_b    = (const float*)d_in[15];
  const float* bn2_g      = (const float*)d_in[16];
  const float* bn2_b      = (const float*)d_in[17];
  const float* bn2_m      = (const float*)d_in[18];
  const float* bn2_v      = (const float*)d_in[19];
  const float* subj_w     = (const float*)d_in[20];
  const float* subj_b     = (const float*)d_in[21];
  const float* obj_w      = (const float*)d_in[22];
  const float* obj_b      = (const float*)d_in[23];
  const float* vr_w       = (const float*)d_in[24];
  const float* vr_b       = (const float*)d_in[25];
  const float* emb1       = (const float*)d_in[26];
  const float* emb2       = (const float*)d_in[27];
  const float* bil_w      = (const float*)d_in[28];
  const float* bil_b      = (const float*)d_in[29];
  const float* lin_w      = (const float*)d_in[30];
  const float* lin_b      = (const float*)d_in[31];
  const float* proj_w     = (const float*)d_in[32];
  const float* proj_b     = (const float*)d_in[33];
  const float* ac_w       = (const float*)d_in[34];
  const float* ac_b       = (const float*)d_in[35];

  float* ws = (float*)d_ws;
  float* s_mat  = ws + OFF_S;
  float* o_mat  = ws + OFF_O;
  float* z1     = ws + OFF_Z1;
  float* bilbuf = ws + OFF_BIL;
  float* rel    = ws + OFF_REL;
  float* ubuf   = ws + OFF_UBUF;
  float* x1     = ws + OFF_X1;
  float* xp     = ws + OFF_XP;
  float* pvr    = ws + OFF_PVR;
  float* pbil   = ws + OFF_PBIL;
  int*   ints   = (int*)(ws + OFF_INTS);
  int* counts = ints; int* starts = ints + 16; int* pos = ints + 32;
  float* out = (float*)d_out;

  dim3 blk(256);

  // subj / obj linears (gathered rows of features) -> s_mat/o_mat cols [0,512)
  {
    GP g{}; g.A = features; g.B = subj_w; g.bias = subj_b; g.C = s_mat;
    g.gidx = pair_idx; g.goff = 0; g.M = 256; g.N = 512; g.K = 2048;
    g.ldc = 712; g.coff = 0; g.kChunk = 2048;
    gemm_k<0><<<dim3(8,4,1), blk, 0, stream>>>(g);
    g.goff = 1; g.B = obj_w; g.bias = obj_b; g.C = o_mat;
    gemm_k<0><<<dim3(8,4,1), blk, 0, stream>>>(g);
  }
  // embedding concat -> cols [512,712)
  emb_k<<<dim3(400), blk, 0, stream>>>(pair_idx, labels, emb1, emb2, s_mat, o_mat);

  // union 1x1 conv as GEMM -> ubuf[(n,q)][oc]
  {
    GP g{}; g.A = union_feat; g.B = w_union; g.bias = b_union; g.C = ubuf;
    g.M = 12544; g.N = 256; g.K = 1024; g.ldc = 256; g.coff = 0; g.kChunk = 1024;
    gemm_k<5><<<dim3(4,196,1), blk, 0, stream>>>(g);
  }

  // conv1 + relu + bn1 -> x1 ; maxpool -> xp
  conv1_k<<<dim3(1792), blk, 0, stream>>>(spatial, conv1_w, conv1_b,
                                          bn1_g, bn1_b, bn1_m, bn1_v, x1);
  pool_k<<<dim3(6272), blk, 0, stream>>>(x1, xp);

  // conv2 (implicit GEMM) + relu + bn2, accumulated into ubuf
  {
    GP g{}; g.A = xp; g.B = conv2_w; g.bias = conv2_b; g.C = ubuf;
    g.M = 12544; g.N = 256; g.K = 1152; g.ldc = 256; g.coff = 0; g.kChunk = 1152;
    g.bn_g = bn2_g; g.bn_b = bn2_b; g.bn_m = bn2_m; g.bn_v = bn2_v;
    gemm_k<6><<<dim3(4,196,1), blk, 0, stream>>>(g);
  }

  // vr linear (split-K 8) -> partials -> rel[:,1424:1936]
  {
    GP g{}; g.A = ubuf; g.B = vr_w; g.C = pvr;
    g.M = 256; g.N = 512; g.K = 12544; g.kChunk = 1568;
    gemm_k<2><<<dim3(8,4,8), blk, 0, stream>>>(g);
    reduce_k<<<dim3(512), blk, 0, stream>>>(pvr, vr_b, rel, 8, 256*512, 512, 1936, 1424);
  }

  // lin: concat(s,o) @ lin_w^T -> z1
  {
    GP g{}; g.A = s_mat; g.A2 = o_mat; g.B = lin_w; g.bias = lin_b; g.C = z1;
    g.M = 256; g.N = 712; g.K = 1424; g.ldc = 712; g.coff = 0; g.kChunk = 1424;
    gemm_k<3><<<dim3(12,4,1), blk, 0, stream>>>(g);
  }

  // bilinear: bf16-split MFMA, split-K 48, 8-wave blocks -> partials -> bilbuf
  bil_mfma_k<<<dim3(12, BILSPLIT), dim3(512), 0, stream>>>(s_mat, o_mat, bil_w, pbil);
  reduce_k<<<dim3(712), blk, 0, stream>>>(pbil, bil_b, bilbuf, BILSPLIT, 256*712, 712, 712, 0);

  // proj: relu(concat(z1,bil)) @ proj_w^T -> rel[:,0:1424]
  {
    GP g{}; g.A = z1; g.A2 = bilbuf; g.B = proj_w; g.bias = proj_b; g.C = rel;
    g.M = 256; g.N = 1424; g.K = 1424; g.ldc = 1936; g.coff = 0; g.kChunk = 1424;
    gemm_k<4><<<dim3(23,4,1), blk, 0, stream>>>(g);
  }

  // segments, memory zero + mask, scatter, pooled max
  seg_k<<<dim3(1), blk, 0, stream>>>(im_idx, counts, starts, pos);
  zeromask_k<<<dim3((SZ_MEM + SZ_MASK + 255)/256), blk, 0, stream>>>(out, counts);
  scatter_k<<<dim3(256), blk, 0, stream>>>(rel, pos, im_idx, out);
  pooled_k<<<dim3(8,16), blk, 0, stream>>>(rel, starts, counts, out);

  // act = sigmoid(pooled @ ac_w^T + ac_b)
  {
    GP g{}; g.A = out + OFF_POOLED; g.B = ac_w; g.bias = ac_b; g.C = out + OFF_ACT;
    g.M = 16; g.N = 157; g.K = 1936; g.ldc = 157; g.coff = 0; g.kChunk = 1936;
    gemm_k<8><<<dim3(3,1,1), blk, 0, stream>>>(g);
  }
}

// Round 5
// 3843.082 us; speedup vs baseline: 1.9741x; 1.0351x over previous
//
#include <hip/hip_runtime.h>
#include <math.h>

#define DEV __device__ __forceinline__

// ---- problem constants ----
#define PP    256          // pairs
#define BIMG  16
#define HB    712          // bilinear dim
#define KBIL  (712*712)    // 506944
#define KSTEPS (KBIL/32)   // 15842
#define DRELC 1936
#define BILSPLIT 48
#define BILCH   331        // ceil(15842/48)

// ---- d_out layout (floats) ----
#define SZ_ACT    (16*157)
#define OFF_ACT   0
#define OFF_POOLED (SZ_ACT)
#define SZ_POOLED (16*1936)
#define OFF_MEM   (OFF_POOLED + SZ_POOLED)
#define SZ_MEM    (24*16*1936)
#define OFF_MASK  (OFF_MEM + SZ_MEM)
#define SZ_MASK   (16*24)

// ---- ws layout (floats) ----
#define OFF_S     0
#define OFF_O     (OFF_S + 256*712)
#define OFF_Z1    (OFF_O + 256*712)
#define OFF_BIL   (OFF_Z1 + 256*712)
#define OFF_REL   (OFF_BIL + 256*712)
#define OFF_UBUF  (OFF_REL + 256*1936)
#define OFF_XP    (OFF_UBUF + 12544*256)
#define OFF_SHARED (OFF_XP + 256*128*49)
#define OFF_X1    OFF_SHARED                       // 256*128*196 floats
#define OFF_PVR   OFF_SHARED                       // 8*256*512
// pbil (48*256*712 = 8.75M floats) aliases ubuf+xp+shared, all dead
// by the time the bilinear runs.
#define OFF_PBIL  OFF_UBUF
#define SZ_SHARED (256*128*196)                    // max(x1, pvr)
#define OFF_INTS  (OFF_SHARED + SZ_SHARED)

typedef __bf16 bf16x8 __attribute__((ext_vector_type(8)));
typedef float  f32x4  __attribute__((ext_vector_type(4)));

// ============================================================
// Bilinear via bf16-split MFMA.
// C[n][c] = sum_k A[n,k]*W[c,k], A[n,k]=s[n,k/712]*o[n,k%712].
// 3-term split: ahi*whi + ahi*wlo + alo*whi  (rel err ~2^-16/term).
// Block: 128 rows x 64 cols, 4 waves (each 2 row-frags of 16).
// Grid (12 col-tiles, 2 row-halves, 48 k-chunks) = 1152 blocks
// -> 4 blocks/CU resident (LDS 36.9KB x4 = 147KB).
// W staged to LDS hi/lo bf16, row stride 72 elems (144 B).
// s/o rows for z+1 prefetched into registers (T14).
// ============================================================
struct Araw { float s0, s1; float4 o00, o01, o10, o11; };

__global__ __launch_bounds__(256) void bil_mfma_k(
    const float* __restrict__ s, const float* __restrict__ o,
    const float* __restrict__ W, float* __restrict__ part) {
  __shared__ __align__(16) __bf16 Wsh[2][2][64*72];

  const int tid = threadIdx.x;
  const int C0 = blockIdx.x * 64;
  const int rowBase = blockIdx.y * 128;
  const int z0 = blockIdx.z * BILCH;
  const int zEnd = min(KSTEPS, z0 + BILCH);

  // staging role: 64 rows x 32 floats; 4 threads/row, 8 floats each
  const int srow = tid >> 2;
  const int koff = (tid & 3) * 8;
  const int sc = C0 + srow;
  const float* wbase = (sc < 712) ? (W + (size_t)sc * KBIL + koff) : (const float*)0;

  // compute role
  const int wv = tid >> 6, lane = tid & 63;
  const int lr = lane & 15, lg = lane >> 4;
  const int n0 = rowBase + wv * 32 + lr;   // rf=0 row; rf=1 adds +16

  f32x4 acc[2][4];
  #pragma unroll
  for (int a = 0; a < 2; a++)
    #pragma unroll
    for (int b = 0; b < 4; b++) { acc[a][b][0]=0.f; acc[a][b][1]=0.f; acc[a][b][2]=0.f; acc[a][b][3]=0.f; }

  auto stage_load = [&](int z, float4& va, float4& vb) {
    if (wbase) {
      const float* p = wbase + (size_t)z * 32;
      va = *(const float4*)p;
      vb = *(const float4*)(p + 4);
    } else {
      va = make_float4(0.f,0.f,0.f,0.f);
      vb = make_float4(0.f,0.f,0.f,0.f);
    }
  };
  auto stage_write = [&](int buf, const float4& va, const float4& vb) {
    float t[8] = {va.x, va.y, va.z, va.w, vb.x, vb.y, vb.z, vb.w};
    bf16x8 hi, lo;
    #pragma unroll
    for (int i = 0; i < 8; i++) {
      float p = t[i];
      __bf16 h = (__bf16)p;
      hi[i] = h;
      lo[i] = (__bf16)(p - (float)h);
    }
    *(bf16x8*)&Wsh[buf][0][srow*72 + koff] = hi;
    *(bf16x8*)&Wsh[buf][1][srow*72 + koff] = lo;
  };
  auto aload = [&](int z) -> Araw {
    Araw a;
    const int kk = z * 32 + lg * 8;
    const int h = kk / 712;
    const int t = kk - h * 712;          // multiple of 8, <=704 -> row-safe
    const float* or0 = o + n0 * 712 + t;
    const float* or1 = o + (n0 + 16) * 712 + t;
    a.s0 = s[n0 * 712 + h];
    a.s1 = s[(n0 + 16) * 712 + h];
    a.o00 = *(const float4*)or0; a.o01 = *(const float4*)(or0 + 4);
    a.o10 = *(const float4*)or1; a.o11 = *(const float4*)(or1 + 4);
    return a;
  };

  { float4 va, vb; stage_load(z0, va, vb); stage_write(0, va, vb); }
  Araw cura = aload(z0);
  __syncthreads();

  for (int z = z0; z < zEnd; ++z) {
    const int cur = (z - z0) & 1;
    const bool pf = (z + 1 < zEnd);
    float4 va, vb;
    Araw nxta;
    if (pf) { stage_load(z + 1, va, vb); nxta = aload(z + 1); }

    // ---- build A fragments from current regs ----
    bf16x8 ahi[2], alo[2];
    {
      float p0[8] = {cura.o00.x,cura.o00.y,cura.o00.z,cura.o00.w,
                     cura.o01.x,cura.o01.y,cura.o01.z,cura.o01.w};
      float p1[8] = {cura.o10.x,cura.o10.y,cura.o10.z,cura.o10.w,
                     cura.o11.x,cura.o11.y,cura.o11.z,cura.o11.w};
      #pragma unroll
      for (int i = 0; i < 8; i++) {
        float a0 = cura.s0 * p0[i];
        __bf16 h0 = (__bf16)a0;
        ahi[0][i] = h0; alo[0][i] = (__bf16)(a0 - (float)h0);
        float a1 = cura.s1 * p1[i];
        __bf16 h1 = (__bf16)a1;
        ahi[1][i] = h1; alo[1][i] = (__bf16)(a1 - (float)h1);
      }
    }

    // ---- MFMA: 4 col-frags x 2 row-frags x 3 terms ----
    #pragma unroll
    for (int cf = 0; cf < 4; cf++) {
      bf16x8 bhi = *(bf16x8*)&Wsh[cur][0][(cf*16 + lr)*72 + lg*8];
      bf16x8 blo = *(bf16x8*)&Wsh[cur][1][(cf*16 + lr)*72 + lg*8];
      #pragma unroll
      for (int rf = 0; rf < 2; rf++) {
        acc[rf][cf] = __builtin_amdgcn_mfma_f32_16x16x32_bf16(ahi[rf], bhi, acc[rf][cf], 0, 0, 0);
        acc[rf][cf] = __builtin_amdgcn_mfma_f32_16x16x32_bf16(ahi[rf], blo, acc[rf][cf], 0, 0, 0);
        acc[rf][cf] = __builtin_amdgcn_mfma_f32_16x16x32_bf16(alo[rf], bhi, acc[rf][cf], 0, 0, 0);
      }
    }

    if (pf) { stage_write(cur ^ 1, va, vb); cura = nxta; }
    __syncthreads();
  }

  // ---- epilogue: partials [z][256][712] ----
  const int bz = blockIdx.z;
  #pragma unroll
  for (int rf = 0; rf < 2; rf++) {
    #pragma unroll
    for (int cf = 0; cf < 4; cf++) {
      const int c = C0 + cf*16 + lr;
      if (c >= 712) continue;
      #pragma unroll
      for (int i = 0; i < 4; i++) {
        const int n = rowBase + wv*32 + rf*16 + lg*4 + i;  // D: row=(lane>>4)*4+i
        part[((size_t)bz*256 + n)*712 + c] = acc[rf][cf][i];
      }
    }
  }
}

struct GP {
  const float* A; const float* A2; const float* B; const float* bias;
  float* C;
  const int* gidx; int goff;
  int M, N, K;
  int ldc, coff;
  int kChunk;
  const float* bn_g; const float* bn_b; const float* bn_m; const float* bn_v;
};

// modes:
// 0: A row-gathered via gidx (features)         epi: +bias -> C
// 2: plain A (ubuf rows), plain B (vr_w)        epi: partial C[z][M][N]
// 3: A = concat(s,o)                            epi: +bias -> C
// 4: A = relu(concat(z1,bil))                   epi: +bias -> C
// 5: A = union_feat gather [(n,q)][ic]          epi: +bias -> ubuf[n][oc][q]
// 6: A = im2col(xp) 3x3 pad1                    epi: bn2(relu(+bias)) += ubuf[n][oc][q]
// 8: plain A                                    epi: sigmoid(+bias) -> C

template<int MODE>
DEV float loadA(const GP& p, int r, int k) {
  if (MODE == 0) { int fr = p.gidx[2*r + p.goff]; return p.A[fr*2048 + k]; }
  if (MODE == 2 || MODE == 8) return p.A[r*p.K + k];
  if (MODE == 3) return (k < 712) ? p.A[r*712 + k] : p.A2[r*712 + (k-712)];
  if (MODE == 4) { float v = (k < 712) ? p.A[r*712 + k] : p.A2[r*712 + (k-712)];
                   return fmaxf(v, 0.f); }
  if (MODE == 5) { int n = r/49, q = r - n*49; return p.A[(n*1024 + k)*49 + q]; }
  if (MODE == 6) {
    int n = r/49, q = r - n*49; int py = q/7, px = q - py*7;
    int ic = k/9, k9 = k - ic*9; int dy = k9/3, dx = k9 - dy*3;
    int iy = py + dy - 1, ix = px + dx - 1;
    if ((unsigned)iy >= 7u || (unsigned)ix >= 7u) return 0.f;
    return p.A[(n*128 + ic)*49 + iy*7 + ix];
  }
  return 0.f;
}

template<int MODE>
DEV float loadB(const GP& p, int c, int k) {
  return p.B[c*p.K + k];
}

template<int MODE>
__global__ __launch_bounds__(256) void gemm_k(GP p) {
  __shared__ float As[16][68];
  __shared__ float Bs[16][68];
  const int tid = threadIdx.x;
  const int tx = tid & 15, ty = tid >> 4;
  const int col0 = blockIdx.x * 64, row0 = blockIdx.y * 64;
  const int kStart = blockIdx.z * p.kChunk;
  const int kEnd = min(p.K, kStart + p.kChunk);
  float acc[4][4] = {};

  for (int kb = kStart; kb < kEnd; kb += 16) {
    if (MODE == 5 || MODE == 6) {
      int r = tid & 63, kk0 = tid >> 6;
      #pragma unroll
      for (int i = 0; i < 4; i++) {
        int kk = kk0 + i*4;
        int gr = row0 + r, gk = kb + kk;
        float v = 0.f;
        if (gr < p.M && gk < kEnd) v = loadA<MODE>(p, gr, gk);
        As[kk][r] = v;
      }
    } else {
      int kk = tid & 15, r0 = tid >> 4;
      #pragma unroll
      for (int i = 0; i < 4; i++) {
        int r = r0 + i*16;
        int gr = row0 + r, gk = kb + kk;
        float v = 0.f;
        if (gr < p.M && gk < kEnd) v = loadA<MODE>(p, gr, gk);
        As[kk][r] = v;
      }
    }
    {
      int kk = tid & 15, c0 = tid >> 4;
      #pragma unroll
      for (int i = 0; i < 4; i++) {
        int c = c0 + i*16;
        int gc = col0 + c, gk = kb + kk;
        float v = 0.f;
        if (gc < p.N && gk < kEnd) v = loadB<MODE>(p, gc, gk);
        Bs[kk][c] = v;
      }
    }
    __syncthreads();
    #pragma unroll
    for (int kk = 0; kk < 16; kk++) {
      float a[4], b[4];
      #pragma unroll
      for (int j = 0; j < 4; j++) a[j] = As[kk][ty*4 + j];
      #pragma unroll
      for (int j = 0; j < 4; j++) b[j] = Bs[kk][tx*4 + j];
      #pragma unroll
      for (int i = 0; i < 4; i++)
        #pragma unroll
        for (int j = 0; j < 4; j++) acc[i][j] += a[i]*b[j];
    }
    __syncthreads();
  }

  #pragma unroll
  for (int i = 0; i < 4; i++) {
    int r = row0 + ty*4 + i;
    if (r >= p.M) continue;
    #pragma unroll
    for (int j = 0; j < 4; j++) {
      int c = col0 + tx*4 + j;
      if (c >= p.N) continue;
      float v = acc[i][j];
      if (MODE == 2) {
        p.C[(size_t)blockIdx.z * p.M * p.N + (size_t)r * p.N + c] = v;
      } else if (MODE == 5) {
        int n = r/49, q = r - n*49;
        p.C[n*12544 + c*49 + q] = v + p.bias[c];
      } else if (MODE == 6) {
        int n = r/49, q = r - n*49;
        float sc = p.bn_g[c] / sqrtf(p.bn_v[c] + 1e-5f);
        float sh = p.bn_b[c] - p.bn_m[c]*sc;
        float t2 = fmaxf(v + p.bias[c], 0.f)*sc + sh;
        p.C[n*12544 + c*49 + q] += t2;
      } else if (MODE == 8) {
        float t2 = v + p.bias[c];
        p.C[r*p.ldc + p.coff + c] = 1.f/(1.f + expf(-t2));
      } else {
        p.C[r*p.ldc + p.coff + c] = v + p.bias[c];
      }
    }
  }
}

__global__ __launch_bounds__(256) void reduce_k(const float* __restrict__ part,
    const float* __restrict__ bias, float* __restrict__ out,
    int S, int MN, int N, int ldc, int coff) {
  int i = blockIdx.x*256 + threadIdx.x;
  if (i >= MN) return;
  float s = 0.f;
  for (int z = 0; z < S; z++) s += part[(size_t)z*MN + i];
  int r = i / N, c = i - r*N;
  out[r*ldc + coff + c] = s + bias[c];
}

__global__ __launch_bounds__(256) void emb_k(const int* __restrict__ pi,
    const int* __restrict__ labels, const float* __restrict__ e1,
    const float* __restrict__ e2, float* __restrict__ s, float* __restrict__ o) {
  int i = blockIdx.x*256 + threadIdx.x;
  if (i >= 2*256*200) return;
  int which = i / (256*200); int rest = i - which*(256*200);
  int n = rest / 200; int j = rest - n*200;
  int lab = labels[pi[2*n + which]];
  float v = which ? e2[lab*200 + j] : e1[lab*200 + j];
  (which ? o : s)[n*712 + 512 + j] = v;
}

__global__ __launch_bounds__(256) void conv1_k(const float* __restrict__ in,
    const float* __restrict__ w, const float* __restrict__ bias,
    const float* __restrict__ g, const float* __restrict__ bt,
    const float* __restrict__ m, const float* __restrict__ vv,
    float* __restrict__ out) {
  int idx = blockIdx.x*256 + threadIdx.x;
  if (idx >= 256*128*14) return;
  int oy = idx % 14; int t = idx / 14; int c = t & 127; int n = t >> 7;
  float acc[14];
  float b0 = bias[c];
  #pragma unroll
  for (int ox = 0; ox < 14; ox++) acc[ox] = b0;
  for (int ci = 0; ci < 2; ci++) {
    #pragma unroll
    for (int ky = 0; ky < 7; ky++) {
      int iy = oy*2 - 3 + ky;
      if ((unsigned)iy >= 27u) continue;
      const float* ir = in + ((n*2 + ci)*27 + iy)*27;
      const float* wr = w + ((c*2 + ci)*7 + ky)*7;
      float iv[27];
      #pragma unroll
      for (int x = 0; x < 27; x++) iv[x] = ir[x];
      float wk[7];
      #pragma unroll
      for (int kx = 0; kx < 7; kx++) wk[kx] = wr[kx];
      #pragma unroll
      for (int kx = 0; kx < 7; kx++)
        #pragma unroll
        for (int ox = 0; ox < 14; ox++) {
          int ix = ox*2 - 3 + kx;
          if (ix >= 0 && ix < 27) acc[ox] += iv[ix]*wk[kx];
        }
    }
  }
  float sc = g[c] / sqrtf(vv[c] + 1e-5f);
  float sh = bt[c] - m[c]*sc;
  float* orow = out + ((n*128 + c)*14 + oy)*14;
  #pragma unroll
  for (int ox = 0; ox < 14; ox++) orow[ox] = fmaxf(acc[ox], 0.f)*sc + sh;
}

__global__ __launch_bounds__(256) void pool_k(const float* __restrict__ x1,
                                              float* __restrict__ xp) {
  int idx = blockIdx.x*256 + threadIdx.x;
  if (idx >= 256*128*49) return;
  int px = idx % 7; int t = idx / 7; int py = t % 7; t /= 7;
  int c = t & 127; int n = t >> 7;
  float mx = -INFINITY;
  for (int dy = 0; dy < 3; dy++) {
    int y = py*2 - 1 + dy;
    if ((unsigned)y >= 14u) continue;
    for (int dx = 0; dx < 3; dx++) {
      int x = px*2 - 1 + dx;
      if ((unsigned)x >= 14u) continue;
      mx = fmaxf(mx, x1[((n*128 + c)*14 + y)*14 + x]);
    }
  }
  xp[((n*128 + c)*7 + py)*7 + px] = mx;
}

__global__ __launch_bounds__(256) void seg_k(const int* __restrict__ im,
    int* __restrict__ counts, int* __restrict__ starts, int* __restrict__ pos) {
  __shared__ int c[16], s[16];
  int tid = threadIdx.x;
  if (tid < 16) c[tid] = 0;
  __syncthreads();
  atomicAdd(&c[im[tid]], 1);
  __syncthreads();
  if (tid == 0) { int run = 0; for (int b = 0; b < 16; b++) { s[b] = run; run += c[b]; } }
  __syncthreads();
  if (tid < 16) { counts[tid] = c[tid]; starts[tid] = s[tid]; }
  pos[tid] = tid - s[im[tid]];
}

__global__ __launch_bounds__(256) void zeromask_k(float* __restrict__ out,
                                                  const int* __restrict__ counts) {
  int i = blockIdx.x*256 + threadIdx.x;
  if (i < SZ_MEM) { out[OFF_MEM + i] = 0.f; return; }
  int j = i - SZ_MEM;
  if (j < SZ_MASK) {
    int b = j / 24, l = j - b*24;
    out[OFF_MASK + j] = (l >= counts[b]) ? 1.f : 0.f;
  }
}

__global__ __launch_bounds__(256) void scatter_k(const float* __restrict__ rel,
    const int* __restrict__ pos, const int* __restrict__ im, float* __restrict__ out) {
  int n = blockIdx.x;
  int l = pos[n], b = im[n];
  float* dst = out + OFF_MEM + ((size_t)l*16 + b)*1936;
  const float* src = rel + (size_t)n*1936;
  for (int d = threadIdx.x; d < 1936; d += 256) dst[d] = src[d];
}

__global__ __launch_bounds__(256) void pooled_k(const float* __restrict__ rel,
    const int* __restrict__ starts, const int* __restrict__ counts,
    float* __restrict__ out) {
  int b = blockIdx.y;
  int d = blockIdx.x*256 + threadIdx.x;
  if (d >= 1936) return;
  int st = starts[b], ct = counts[b];
  float mx = -INFINITY;
  for (int i = 0; i < ct; i++) mx = fmaxf(mx, rel[(size_t)(st + i)*1936 + d]);
  out[OFF_POOLED + b*1936 + d] = mx;
}

extern "C" void kernel_launch(void* const* d_in, const int* in_sizes, int n_in,
                              void* d_out, int out_size, void* d_ws, size_t ws_size,
                              hipStream_t stream) {
  const float* features   = (const float*)d_in[0];
  const int*   pair_idx   = (const int*)d_in[1];
  const int*   im_idx     = (const int*)d_in[2];
  const int*   labels     = (const int*)d_in[3];
  const float* union_feat = (const float*)d_in[4];
  const float* spatial    = (const float*)d_in[5];
  const float* w_union    = (const float*)d_in[6];
  const float* b_union    = (const float*)d_in[7];
  const float* conv1_w    = (const float*)d_in[8];
  const float* conv1_b    = (const float*)d_in[9];
  const float* bn1_g      = (const float*)d_in[10];
  const float* bn1_b      = (const float*)d_in[11];
  const float* bn1_m      = (const float*)d_in[12];
  const float* bn1_v      = (const float*)d_in[13];
  const float* conv2_w    = (const float*)d_in[14];
  const float* conv2_b    = (const float*)d_in[15];
  const float* bn2_g      = (const float*)d_in[16];
  const float* bn2_b      = (const float*)d_in[17];
  const float* bn2_m      = (const float*)d_in[18];
  const float* bn2_v      = (const float*)d_in[19];
  const float* subj_w     = (const float*)d_in[20];
  const float* subj_b     = (const float*)d_in[21];
  const float* obj_w      = (const float*)d_in[22];
  const float* obj_b      = (const float*)d_in[23];
  const float* vr_w       = (const float*)d_in[24];
  const float* vr_b       = (const float*)d_in[25];
  const float* emb1       = (const float*)d_in[26];
  const float* emb2       = (const float*)d_in[27];
  const float* bil_w      = (const float*)d_in[28];
  const float* bil_b      = (const float*)d_in[29];
  const float* lin_w      = (const float*)d_in[30];
  const float* lin_b      = (const float*)d_in[31];
  const float* proj_w     = (const float*)d_in[32];
  const float* proj_b     = (const float*)d_in[33];
  const float* ac_w       = (const float*)d_in[34];
  const float* ac_b       = (const float*)d_in[35];

  float* ws = (float*)d_ws;
  float* s_mat  = ws + OFF_S;
  float* o_mat  = ws + OFF_O;
  float* z1     = ws + OFF_Z1;
  float* bilbuf = ws + OFF_BIL;
  float* rel    = ws + OFF_REL;
  float* ubuf   = ws + OFF_UBUF;   // layout [n][oc][q] = [256][256][49]
  float* x1     = ws + OFF_X1;
  float* xp     = ws + OFF_XP;
  float* pvr    = ws + OFF_PVR;
  float* pbil   = ws + OFF_PBIL;
  int*   ints   = (int*)(ws + OFF_INTS);
  int* counts = ints; int* starts = ints + 16; int* pos = ints + 32;
  float* out = (float*)d_out;

  dim3 blk(256);

  // subj / obj linears (gathered rows of features) -> s_mat/o_mat cols [0,512)
  {
    GP g{}; g.A = features; g.B = subj_w; g.bias = subj_b; g.C = s_mat;
    g.gidx = pair_idx; g.goff = 0; g.M = 256; g.N = 512; g.K = 2048;
    g.ldc = 712; g.coff = 0; g.kChunk = 2048;
    gemm_k<0><<<dim3(8,4,1), blk, 0, stream>>>(g);
    g.goff = 1; g.B = obj_w; g.bias = obj_b; g.C = o_mat;
    gemm_k<0><<<dim3(8,4,1), blk, 0, stream>>>(g);
  }
  // embedding concat -> cols [512,712)
  emb_k<<<dim3(400), blk, 0, stream>>>(pair_idx, labels, emb1, emb2, s_mat, o_mat);

  // union 1x1 conv as GEMM -> ubuf[n][oc][q] (scatter epilogue)
  {
    GP g{}; g.A = union_feat; g.B = w_union; g.bias = b_union; g.C = ubuf;
    g.M = 12544; g.N = 256; g.K = 1024; g.kChunk = 1024;
    gemm_k<5><<<dim3(4,196,1), blk, 0, stream>>>(g);
  }

  // conv1 + relu + bn1 -> x1 ; maxpool -> xp
  conv1_k<<<dim3(1792), blk, 0, stream>>>(spatial, conv1_w, conv1_b,
                                          bn1_g, bn1_b, bn1_m, bn1_v, x1);
  pool_k<<<dim3(6272), blk, 0, stream>>>(x1, xp);

  // conv2 (implicit GEMM) + relu + bn2, accumulated into ubuf[n][oc][q]
  {
    GP g{}; g.A = xp; g.B = conv2_w; g.bias = conv2_b; g.C = ubuf;
    g.M = 12544; g.N = 256; g.K = 1152; g.kChunk = 1152;
    g.bn_g = bn2_g; g.bn_b = bn2_b; g.bn_m = bn2_m; g.bn_v = bn2_v;
    gemm_k<6><<<dim3(4,196,1), blk, 0, stream>>>(g);
  }

  // vr linear: ubuf [256][12544] contiguous rows x vr_w [512][12544]
  // (split-K 8) -> partials -> rel[:,1424:1936]
  {
    GP g{}; g.A = ubuf; g.B = vr_w; g.C = pvr;
    g.M = 256; g.N = 512; g.K = 12544; g.kChunk = 1568;
    gemm_k<2><<<dim3(8,4,8), blk, 0, stream>>>(g);
    reduce_k<<<dim3(512), blk, 0, stream>>>(pvr, vr_b, rel, 8, 256*512, 512, 1936, 1424);
  }

  // lin: concat(s,o) @ lin_w^T -> z1
  {
    GP g{}; g.A = s_mat; g.A2 = o_mat; g.B = lin_w; g.bias = lin_b; g.C = z1;
    g.M = 256; g.N = 712; g.K = 1424; g.ldc = 712; g.coff = 0; g.kChunk = 1424;
    gemm_k<3><<<dim3(12,4,1), blk, 0, stream>>>(g);
  }

  // bilinear: bf16-split MFMA, row-split x2, split-K 48 -> partials -> bilbuf
  bil_mfma_k<<<dim3(12, 2, BILSPLIT), dim3(256), 0, stream>>>(s_mat, o_mat, bil_w, pbil);
  reduce_k<<<dim3(712), blk, 0, stream>>>(pbil, bil_b, bilbuf, BILSPLIT, 256*712, 712, 712, 0);

  // proj: relu(concat(z1,bil)) @ proj_w^T -> rel[:,0:1424]
  {
    GP g{}; g.A = z1; g.A2 = bilbuf; g.B = proj_w; g.bias = proj_b; g.C = rel;
    g.M = 256; g.N = 1424; g.K = 1424; g.ldc = 1936; g.coff = 0; g.kChunk = 1424;
    gemm_k<4><<<dim3(23,4,1), blk, 0, stream>>>(g);
  }

  // segments, memory zero + mask, scatter, pooled max
  seg_k<<<dim3(1), blk, 0, stream>>>(im_idx, counts, starts, pos);
  zeromask_k<<<dim3((SZ_MEM + SZ_MASK + 255)/256), blk, 0, stream>>>(out, counts);
  scatter_k<<<dim3(256), blk, 0, stream>>>(rel, pos, im_idx, out);
  pooled_k<<<dim3(8,16), blk, 0, stream>>>(rel, starts, counts, out);

  // act = sigmoid(pooled @ ac_w^T + ac_b)
  {
    GP g{}; g.A = out + OFF_POOLED; g.B = ac_w; g.bias = ac_b; g.C = out + OFF_ACT;
    g.M = 16; g.N = 157; g.K = 1936; g.ldc = 157; g.coff = 0; g.kChunk = 1936;
    gemm_k<8><<<dim3(3,1,1), blk, 0, stream>>>(g);
  }
}

// Round 6
// 3719.970 us; speedup vs baseline: 2.0394x; 1.0331x over previous
//
#include <hip/hip_runtime.h>
#include <math.h>

#define DEV __device__ __forceinline__

// ---- problem constants ----
#define PP    256          // pairs
#define BIMG  16
#define HB    712          // bilinear dim
#define KBIL  (712*712)    // 506944
#define KSTEPS (KBIL/32)   // 15842
#define DRELC 1936
#define BILSPLIT 42
#define BILCH   378        // ceil(15842/42); grid 12*2*42=1008 ~ 3.94 blocks/CU (fully resident)

// ---- d_out layout (floats) ----
#define SZ_ACT    (16*157)
#define OFF_ACT   0
#define OFF_POOLED (SZ_ACT)
#define SZ_POOLED (16*1936)
#define OFF_MEM   (OFF_POOLED + SZ_POOLED)
#define SZ_MEM    (24*16*1936)
#define OFF_MASK  (OFF_MEM + SZ_MEM)
#define SZ_MASK   (16*24)

// ---- ws layout (floats) ----
#define OFF_S     0
#define OFF_O     (OFF_S + 256*712)
#define OFF_Z1    (OFF_O + 256*712)
#define OFF_BIL   (OFF_Z1 + 256*712)
#define OFF_REL   (OFF_BIL + 256*712)
#define OFF_UBUF  (OFF_REL + 256*1936)
#define OFF_XP    (OFF_UBUF + 12544*256)
#define OFF_SHARED (OFF_XP + 256*128*49)
#define OFF_X1    OFF_SHARED                       // 256*128*196 floats
#define OFF_PVR   OFF_SHARED                       // 8*256*512
// pbil (42*256*712 = 7.66M floats) aliases ubuf+xp+shared (11.24M), all dead
// by the time the bilinear runs.
#define OFF_PBIL  OFF_UBUF
#define SZ_SHARED (256*128*196)                    // max(x1, pvr)
#define OFF_INTS  (OFF_SHARED + SZ_SHARED)

typedef __bf16 bf16x8 __attribute__((ext_vector_type(8)));
typedef float  f32x4  __attribute__((ext_vector_type(4)));

// ============================================================
// Bilinear via bf16-split MFMA, depth-2 software pipeline.
// C[n][c] = sum_k A[n,k]*W[c,k], A[n,k]=s[n,k/712]*o[n,k%712].
// 3-term split: ahi*whi + ahi*wlo + alo*whi  (rel err ~2^-16/term).
// Block: 128 rows x 64 cols, 4 waves. Grid (12,2,42) = 1008 blocks,
// 4 blocks/CU resident (LDS 20.5KB, VGPR capped 128 via launch_bounds).
// W loads issued 2 z-steps before their ds_write (reg FIFO s0/s1),
// so L3/HBM latency hides under 2 steps of compute.
// ============================================================
struct Araw { float s0, s1; float4 o00, o01, o10, o11; };

__global__ __launch_bounds__(256, 4) void bil_mfma_k(
    const float* __restrict__ s, const float* __restrict__ o,
    const float* __restrict__ W, float* __restrict__ part) {
  __shared__ __align__(16) __bf16 Wsh[2][2][64*40];   // [buf][hi/lo][row*40+k]

  const int tid = threadIdx.x;
  const int C0 = blockIdx.x * 64;
  const int rowBase = blockIdx.y * 128;
  const int z0 = blockIdx.z * BILCH;
  const int zEnd = min(KSTEPS, z0 + BILCH);

  // staging role: 64 rows x 32 floats; 4 threads/row, 8 floats each
  const int srow = tid >> 2;
  const int koff = (tid & 3) * 8;
  const int sc = C0 + srow;
  const float* wbase = (sc < 712) ? (W + (size_t)sc * KBIL + koff) : (const float*)0;

  // compute role
  const int wv = tid >> 6, lane = tid & 63;
  const int lr = lane & 15, lg = lane >> 4;
  const int n0 = rowBase + wv * 32 + lr;   // rf=0 row; rf=1 adds +16

  f32x4 acc[2][4];
  #pragma unroll
  for (int a = 0; a < 2; a++)
    #pragma unroll
    for (int b = 0; b < 4; b++) { acc[a][b][0]=0.f; acc[a][b][1]=0.f; acc[a][b][2]=0.f; acc[a][b][3]=0.f; }

  auto wload = [&](int z, float4& va, float4& vb) {
    if (wbase) {
      const float* p = wbase + (size_t)z * 32;
      va = *(const float4*)p;
      vb = *(const float4*)(p + 4);
    } else {
      va = make_float4(0.f,0.f,0.f,0.f);
      vb = make_float4(0.f,0.f,0.f,0.f);
    }
  };
  auto wstore = [&](int buf, const float4& va, const float4& vb) {
    float t[8] = {va.x, va.y, va.z, va.w, vb.x, vb.y, vb.z, vb.w};
    bf16x8 hi, lo;
    #pragma unroll
    for (int i = 0; i < 8; i++) {
      float p = t[i];
      __bf16 h = (__bf16)p;
      hi[i] = h;
      lo[i] = (__bf16)(p - (float)h);
    }
    *(bf16x8*)&Wsh[buf][0][srow*40 + koff] = hi;
    *(bf16x8*)&Wsh[buf][1][srow*40 + koff] = lo;
  };
  auto aload = [&](int z, Araw& a) {
    const int kk = z * 32 + lg * 8;
    const int h = kk / 712;
    const int t = kk - h * 712;          // multiple of 8, <=704 -> row-safe
    const float* or0 = o + n0 * 712 + t;
    const float* or1 = o + (n0 + 16) * 712 + t;
    a.s0 = s[n0 * 712 + h];
    a.s1 = s[(n0 + 16) * 712 + h];
    a.o00 = *(const float4*)or0; a.o01 = *(const float4*)(or0 + 4);
    a.o10 = *(const float4*)or1; a.o11 = *(const float4*)(or1 + 4);
  };
  auto amake = [&](const Araw& a, bf16x8 (&ahi)[2], bf16x8 (&alo)[2]) {
    float p0[8] = {a.o00.x,a.o00.y,a.o00.z,a.o00.w, a.o01.x,a.o01.y,a.o01.z,a.o01.w};
    float p1[8] = {a.o10.x,a.o10.y,a.o10.z,a.o10.w, a.o11.x,a.o11.y,a.o11.z,a.o11.w};
    #pragma unroll
    for (int i = 0; i < 8; i++) {
      float a0 = a.s0 * p0[i];
      __bf16 h0 = (__bf16)a0;
      ahi[0][i] = h0; alo[0][i] = (__bf16)(a0 - (float)h0);
      float a1 = a.s1 * p1[i];
      __bf16 h1 = (__bf16)a1;
      ahi[1][i] = h1; alo[1][i] = (__bf16)(a1 - (float)h1);
    }
  };
  // buf is a literal at every call site -> static LDS indexing
  auto domfma = [&](int buf, bf16x8 (&ahi)[2], bf16x8 (&alo)[2]) {
    #pragma unroll
    for (int cf = 0; cf < 4; cf++) {
      bf16x8 bhi = *(bf16x8*)&Wsh[buf][0][(cf*16 + lr)*40 + lg*8];
      bf16x8 blo = *(bf16x8*)&Wsh[buf][1][(cf*16 + lr)*40 + lg*8];
      #pragma unroll
      for (int rf = 0; rf < 2; rf++) {
        acc[rf][cf] = __builtin_amdgcn_mfma_f32_16x16x32_bf16(ahi[rf], bhi, acc[rf][cf], 0, 0, 0);
        acc[rf][cf] = __builtin_amdgcn_mfma_f32_16x16x32_bf16(ahi[rf], blo, acc[rf][cf], 0, 0, 0);
        acc[rf][cf] = __builtin_amdgcn_mfma_f32_16x16x32_bf16(alo[rf], bhi, acc[rf][cf], 0, 0, 0);
      }
    }
  };

  // ---- prologue: buf0 <- W(z0); slots s0 <- W(z0+1), s1 <- W(z0+2) in flight
  Araw A0, A1;
  {
    float4 pa, pb;
    wload(z0, pa, pb);
    aload(z0, A0);
    wstore(0, pa, pb);
  }
  float4 s0a, s0b, s1a, s1b;
  wload(min(z0 + 1, zEnd - 1), s0a, s0b);
  wload(min(z0 + 2, zEnd - 1), s1a, s1b);
  __syncthreads();

  // invariants at loop top: buf0 = W(z), A0 = A(z), s0 ~ W(z+1), s1 ~ W(z+2)
  int z = z0;
  for (; z + 1 < zEnd; z += 2) {
    // ---- step z on buf0 ----
    aload(z + 1, A1);
    {
      bf16x8 ahi[2], alo[2];
      amake(A0, ahi, alo);
      domfma(0, ahi, alo);
    }
    wstore(1, s0a, s0b);                     // W(z+1) -> buf1 (load is 2 steps old)
    wload(min(z + 3, zEnd - 1), s0a, s0b);   // refill slot for buf1 next iter
    __syncthreads();
    // ---- step z+1 on buf1 ----
    aload(min(z + 2, zEnd - 1), A0);
    {
      bf16x8 ahi[2], alo[2];
      amake(A1, ahi, alo);
      domfma(1, ahi, alo);
    }
    wstore(0, s1a, s1b);                     // W(z+2) -> buf0
    wload(min(z + 4, zEnd - 1), s1a, s1b);
    __syncthreads();
  }
  if (z < zEnd) {                            // odd tail: buf0 = W(z), A0 = A(z)
    bf16x8 ahi[2], alo[2];
    amake(A0, ahi, alo);
    domfma(0, ahi, alo);
  }

  // ---- epilogue: partials [z][256][712] ----
  const int bz = blockIdx.z;
  #pragma unroll
  for (int rf = 0; rf < 2; rf++) {
    #pragma unroll
    for (int cf = 0; cf < 4; cf++) {
      const int c = C0 + cf*16 + lr;
      if (c >= 712) continue;
      #pragma unroll
      for (int i = 0; i < 4; i++) {
        const int n = rowBase + wv*32 + rf*16 + lg*4 + i;  // D: row=(lane>>4)*4+i
        part[((size_t)bz*256 + n)*712 + c] = acc[rf][cf][i];
      }
    }
  }
}

struct GP {
  const float* A; const float* A2; const float* B; const float* bias;
  float* C;
  const int* gidx; int goff;
  int M, N, K;
  int ldc, coff;
  int kChunk;
  const float* bn_g; const float* bn_b; const float* bn_m; const float* bn_v;
};

// modes:
// 0: A row-gathered via gidx (features)         epi: +bias -> C
// 2: plain A (ubuf rows), plain B (vr_w)        epi: partial C[z][M][N]
// 3: A = concat(s,o)                            epi: +bias -> C
// 4: A = relu(concat(z1,bil))                   epi: +bias -> C
// 5: A = union_feat gather [(n,q)][ic]          epi: +bias -> ubuf[n][oc][q]
// 6: A = im2col(xp) 3x3 pad1                    epi: bn2(relu(+bias)) += ubuf[n][oc][q]
// 8: plain A                                    epi: sigmoid(+bias) -> C

template<int MODE>
DEV float loadA(const GP& p, int r, int k) {
  if (MODE == 0) { int fr = p.gidx[2*r + p.goff]; return p.A[fr*2048 + k]; }
  if (MODE == 2 || MODE == 8) return p.A[r*p.K + k];
  if (MODE == 3) return (k < 712) ? p.A[r*712 + k] : p.A2[r*712 + (k-712)];
  if (MODE == 4) { float v = (k < 712) ? p.A[r*712 + k] : p.A2[r*712 + (k-712)];
                   return fmaxf(v, 0.f); }
  if (MODE == 5) { int n = r/49, q = r - n*49; return p.A[(n*1024 + k)*49 + q]; }
  if (MODE == 6) {
    int n = r/49, q = r - n*49; int py = q/7, px = q - py*7;
    int ic = k/9, k9 = k - ic*9; int dy = k9/3, dx = k9 - dy*3;
    int iy = py + dy - 1, ix = px + dx - 1;
    if ((unsigned)iy >= 7u || (unsigned)ix >= 7u) return 0.f;
    return p.A[(n*128 + ic)*49 + iy*7 + ix];
  }
  return 0.f;
}

template<int MODE>
DEV float loadB(const GP& p, int c, int k) {
  return p.B[c*p.K + k];
}

template<int MODE>
__global__ __launch_bounds__(256) void gemm_k(GP p) {
  __shared__ float As[16][68];
  __shared__ float Bs[16][68];
  const int tid = threadIdx.x;
  const int tx = tid & 15, ty = tid >> 4;
  const int col0 = blockIdx.x * 64, row0 = blockIdx.y * 64;
  const int kStart = blockIdx.z * p.kChunk;
  const int kEnd = min(p.K, kStart + p.kChunk);
  float acc[4][4] = {};

  for (int kb = kStart; kb < kEnd; kb += 16) {
    if (MODE == 5 || MODE == 6) {
      int r = tid & 63, kk0 = tid >> 6;
      #pragma unroll
      for (int i = 0; i < 4; i++) {
        int kk = kk0 + i*4;
        int gr = row0 + r, gk = kb + kk;
        float v = 0.f;
        if (gr < p.M && gk < kEnd) v = loadA<MODE>(p, gr, gk);
        As[kk][r] = v;
      }
    } else {
      int kk = tid & 15, r0 = tid >> 4;
      #pragma unroll
      for (int i = 0; i < 4; i++) {
        int r = r0 + i*16;
        int gr = row0 + r, gk = kb + kk;
        float v = 0.f;
        if (gr < p.M && gk < kEnd) v = loadA<MODE>(p, gr, gk);
        As[kk][r] = v;
      }
    }
    {
      int kk = tid & 15, c0 = tid >> 4;
      #pragma unroll
      for (int i = 0; i < 4; i++) {
        int c = c0 + i*16;
        int gc = col0 + c, gk = kb + kk;
        float v = 0.f;
        if (gc < p.N && gk < kEnd) v = loadB<MODE>(p, gc, gk);
        Bs[kk][c] = v;
      }
    }
    __syncthreads();
    #pragma unroll
    for (int kk = 0; kk < 16; kk++) {
      float a[4], b[4];
      #pragma unroll
      for (int j = 0; j < 4; j++) a[j] = As[kk][ty*4 + j];
      #pragma unroll
      for (int j = 0; j < 4; j++) b[j] = Bs[kk][tx*4 + j];
      #pragma unroll
      for (int i = 0; i < 4; i++)
        #pragma unroll
        for (int j = 0; j < 4; j++) acc[i][j] += a[i]*b[j];
    }
    __syncthreads();
  }

  #pragma unroll
  for (int i = 0; i < 4; i++) {
    int r = row0 + ty*4 + i;
    if (r >= p.M) continue;
    #pragma unroll
    for (int j = 0; j < 4; j++) {
      int c = col0 + tx*4 + j;
      if (c >= p.N) continue;
      float v = acc[i][j];
      if (MODE == 2) {
        p.C[(size_t)blockIdx.z * p.M * p.N + (size_t)r * p.N + c] = v;
      } else if (MODE == 5) {
        int n = r/49, q = r - n*49;
        p.C[n*12544 + c*49 + q] = v + p.bias[c];
      } else if (MODE == 6) {
        int n = r/49, q = r - n*49;
        float sc = p.bn_g[c] / sqrtf(p.bn_v[c] + 1e-5f);
        float sh = p.bn_b[c] - p.bn_m[c]*sc;
        float t2 = fmaxf(v + p.bias[c], 0.f)*sc + sh;
        p.C[n*12544 + c*49 + q] += t2;
      } else if (MODE == 8) {
        float t2 = v + p.bias[c];
        p.C[r*p.ldc + p.coff + c] = 1.f/(1.f + expf(-t2));
      } else {
        p.C[r*p.ldc + p.coff + c] = v + p.bias[c];
      }
    }
  }
}

__global__ __launch_bounds__(256) void reduce_k(const float* __restrict__ part,
    const float* __restrict__ bias, float* __restrict__ out,
    int S, int MN, int N, int ldc, int coff) {
  int i = blockIdx.x*256 + threadIdx.x;
  if (i >= MN) return;
  float s = 0.f;
  for (int z = 0; z < S; z++) s += part[(size_t)z*MN + i];
  int r = i / N, c = i - r*N;
  out[r*ldc + coff + c] = s + bias[c];
}

__global__ __launch_bounds__(256) void emb_k(const int* __restrict__ pi,
    const int* __restrict__ labels, const float* __restrict__ e1,
    const float* __restrict__ e2, float* __restrict__ s, float* __restrict__ o) {
  int i = blockIdx.x*256 + threadIdx.x;
  if (i >= 2*256*200) return;
  int which = i / (256*200); int rest = i - which*(256*200);
  int n = rest / 200; int j = rest - n*200;
  int lab = labels[pi[2*n + which]];
  float v = which ? e2[lab*200 + j] : e1[lab*200 + j];
  (which ? o : s)[n*712 + 512 + j] = v;
}

__global__ __launch_bounds__(256) void conv1_k(const float* __restrict__ in,
    const float* __restrict__ w, const float* __restrict__ bias,
    const float* __restrict__ g, const float* __restrict__ bt,
    const float* __restrict__ m, const float* __restrict__ vv,
    float* __restrict__ out) {
  int idx = blockIdx.x*256 + threadIdx.x;
  if (idx >= 256*128*14) return;
  int oy = idx % 14; int t = idx / 14; int c = t & 127; int n = t >> 7;
  float acc[14];
  float b0 = bias[c];
  #pragma unroll
  for (int ox = 0; ox < 14; ox++) acc[ox] = b0;
  for (int ci = 0; ci < 2; ci++) {
    #pragma unroll
    for (int ky = 0; ky < 7; ky++) {
      int iy = oy*2 - 3 + ky;
      if ((unsigned)iy >= 27u) continue;
      const float* ir = in + ((n*2 + ci)*27 + iy)*27;
      const float* wr = w + ((c*2 + ci)*7 + ky)*7;
      float iv[27];
      #pragma unroll
      for (int x = 0; x < 27; x++) iv[x] = ir[x];
      float wk[7];
      #pragma unroll
      for (int kx = 0; kx < 7; kx++) wk[kx] = wr[kx];
      #pragma unroll
      for (int kx = 0; kx < 7; kx++)
        #pragma unroll
        for (int ox = 0; ox < 14; ox++) {
          int ix = ox*2 - 3 + kx;
          if (ix >= 0 && ix < 27) acc[ox] += iv[ix]*wk[kx];
        }
    }
  }
  float sc = g[c] / sqrtf(vv[c] + 1e-5f);
  float sh = bt[c] - m[c]*sc;
  float* orow = out + ((n*128 + c)*14 + oy)*14;
  #pragma unroll
  for (int ox = 0; ox < 14; ox++) orow[ox] = fmaxf(acc[ox], 0.f)*sc + sh;
}

__global__ __launch_bounds__(256) void pool_k(const float* __restrict__ x1,
                                              float* __restrict__ xp) {
  int idx = blockIdx.x*256 + threadIdx.x;
  if (idx >= 256*128*49) return;
  int px = idx % 7; int t = idx / 7; int py = t % 7; t /= 7;
  int c = t & 127; int n = t >> 7;
  float mx = -INFINITY;
  for (int dy = 0; dy < 3; dy++) {
    int y = py*2 - 1 + dy;
    if ((unsigned)y >= 14u) continue;
    for (int dx = 0; dx < 3; dx++) {
      int x = px*2 - 1 + dx;
      if ((unsigned)x >= 14u) continue;
      mx = fmaxf(mx, x1[((n*128 + c)*14 + y)*14 + x]);
    }
  }
  xp[((n*128 + c)*7 + py)*7 + px] = mx;
}

__global__ __launch_bounds__(256) void seg_k(const int* __restrict__ im,
    int* __restrict__ counts, int* __restrict__ starts, int* __restrict__ pos) {
  __shared__ int c[16], s[16];
  int tid = threadIdx.x;
  if (tid < 16) c[tid] = 0;
  __syncthreads();
  atomicAdd(&c[im[tid]], 1);
  __syncthreads();
  if (tid == 0) { int run = 0; for (int b = 0; b < 16; b++) { s[b] = run; run += c[b]; } }
  __syncthreads();
  if (tid < 16) { counts[tid] = c[tid]; starts[tid] = s[tid]; }
  pos[tid] = tid - s[im[tid]];
}

__global__ __launch_bounds__(256) void zeromask_k(float* __restrict__ out,
                                                  const int* __restrict__ counts) {
  int i = blockIdx.x*256 + threadIdx.x;
  if (i < SZ_MEM) { out[OFF_MEM + i] = 0.f; return; }
  int j = i - SZ_MEM;
  if (j < SZ_MASK) {
    int b = j / 24, l = j - b*24;
    out[OFF_MASK + j] = (l >= counts[b]) ? 1.f : 0.f;
  }
}

__global__ __launch_bounds__(256) void scatter_k(const float* __restrict__ rel,
    const int* __restrict__ pos, const int* __restrict__ im, float* __restrict__ out) {
  int n = blockIdx.x;
  int l = pos[n], b = im[n];
  float* dst = out + OFF_MEM + ((size_t)l*16 + b)*1936;
  const float* src = rel + (size_t)n*1936;
  for (int d = threadIdx.x; d < 1936; d += 256) dst[d] = src[d];
}

__global__ __launch_bounds__(256) void pooled_k(const float* __restrict__ rel,
    const int* __restrict__ starts, const int* __restrict__ counts,
    float* __restrict__ out) {
  int b = blockIdx.y;
  int d = blockIdx.x*256 + threadIdx.x;
  if (d >= 1936) return;
  int st = starts[b], ct = counts[b];
  float mx = -INFINITY;
  for (int i = 0; i < ct; i++) mx = fmaxf(mx, rel[(size_t)(st + i)*1936 + d]);
  out[OFF_POOLED + b*1936 + d] = mx;
}

extern "C" void kernel_launch(void* const* d_in, const int* in_sizes, int n_in,
                              void* d_out, int out_size, void* d_ws, size_t ws_size,
                              hipStream_t stream) {
  const float* features   = (const float*)d_in[0];
  const int*   pair_idx   = (const int*)d_in[1];
  const int*   im_idx     = (const int*)d_in[2];
  const int*   labels     = (const int*)d_in[3];
  const float* union_feat = (const float*)d_in[4];
  const float* spatial    = (const float*)d_in[5];
  const float* w_union    = (const float*)d_in[6];
  const float* b_union    = (const float*)d_in[7];
  const float* conv1_w    = (const float*)d_in[8];
  const float* conv1_b    = (const float*)d_in[9];
  const float* bn1_g      = (const float*)d_in[10];
  const float* bn1_b      = (const float*)d_in[11];
  const float* bn1_m      = (const float*)d_in[12];
  const float* bn1_v      = (const float*)d_in[13];
  const float* conv2_w    = (const float*)d_in[14];
  const float* conv2_b    = (const float*)d_in[15];
  const float* bn2_g      = (const float*)d_in[16];
  const float* bn2_b      = (const float*)d_in[17];
  const float* bn2_m      = (const float*)d_in[18];
  const float* bn2_v      = (const float*)d_in[19];
  const float* subj_w     = (const float*)d_in[20];
  const float* subj_b     = (const float*)d_in[21];
  const float* obj_w      = (const float*)d_in[22];
  const float* obj_b      = (const float*)d_in[23];
  const float* vr_w       = (const float*)d_in[24];
  const float* vr_b       = (const float*)d_in[25];
  const float* emb1       = (const float*)d_in[26];
  const float* emb2       = (const float*)d_in[27];
  const float* bil_w      = (const float*)d_in[28];
  const float* bil_b      = (const float*)d_in[29];
  const float* lin_w      = (const float*)d_in[30];
  const float* lin_b      = (const float*)d_in[31];
  const float* proj_w     = (const float*)d_in[32];
  const float* proj_b     = (const float*)d_in[33];
  const float* ac_w       = (const float*)d_in[34];
  const float* ac_b       = (const float*)d_in[35];

  float* ws = (float*)d_ws;
  float* s_mat  = ws + OFF_S;
  float* o_mat  = ws + OFF_O;
  float* z1     = ws + OFF_Z1;
  float* bilbuf = ws + OFF_BIL;
  float* rel    = ws + OFF_REL;
  float* ubuf   = ws + OFF_UBUF;   // layout [n][oc][q] = [256][256][49]
  float* x1     = ws + OFF_X1;
  float* xp     = ws + OFF_XP;
  float* pvr    = ws + OFF_PVR;
  float* pbil   = ws + OFF_PBIL;
  int*   ints   = (int*)(ws + OFF_INTS);
  int* counts = ints; int* starts = ints + 16; int* pos = ints + 32;
  float* out = (float*)d_out;

  dim3 blk(256);

  // subj / obj linears (gathered rows of features) -> s_mat/o_mat cols [0,512)
  {
    GP g{}; g.A = features; g.B = subj_w; g.bias = subj_b; g.C = s_mat;
    g.gidx = pair_idx; g.goff = 0; g.M = 256; g.N = 512; g.K = 2048;
    g.ldc = 712; g.coff = 0; g.kChunk = 2048;
    gemm_k<0><<<dim3(8,4,1), blk, 0, stream>>>(g);
    g.goff = 1; g.B = obj_w; g.bias = obj_b; g.C = o_mat;
    gemm_k<0><<<dim3(8,4,1), blk, 0, stream>>>(g);
  }
  // embedding concat -> cols [512,712)
  emb_k<<<dim3(400), blk, 0, stream>>>(pair_idx, labels, emb1, emb2, s_mat, o_mat);

  // union 1x1 conv as GEMM -> ubuf[n][oc][q] (scatter epilogue)
  {
    GP g{}; g.A = union_feat; g.B = w_union; g.bias = b_union; g.C = ubuf;
    g.M = 12544; g.N = 256; g.K = 1024; g.kChunk = 1024;
    gemm_k<5><<<dim3(4,196,1), blk, 0, stream>>>(g);
  }

  // conv1 + relu + bn1 -> x1 ; maxpool -> xp
  conv1_k<<<dim3(1792), blk, 0, stream>>>(spatial, conv1_w, conv1_b,
                                          bn1_g, bn1_b, bn1_m, bn1_v, x1);
  pool_k<<<dim3(6272), blk, 0, stream>>>(x1, xp);

  // conv2 (implicit GEMM) + relu + bn2, accumulated into ubuf[n][oc][q]
  {
    GP g{}; g.A = xp; g.B = conv2_w; g.bias = conv2_b; g.C = ubuf;
    g.M = 12544; g.N = 256; g.K = 1152; g.kChunk = 1152;
    g.bn_g = bn2_g; g.bn_b = bn2_b; g.bn_m = bn2_m; g.bn_v = bn2_v;
    gemm_k<6><<<dim3(4,196,1), blk, 0, stream>>>(g);
  }

  // vr linear: ubuf [256][12544] contiguous rows x vr_w [512][12544]
  // (split-K 8) -> partials -> rel[:,1424:1936]
  {
    GP g{}; g.A = ubuf; g.B = vr_w; g.C = pvr;
    g.M = 256; g.N = 512; g.K = 12544; g.kChunk = 1568;
    gemm_k<2><<<dim3(8,4,8), blk, 0, stream>>>(g);
    reduce_k<<<dim3(512), blk, 0, stream>>>(pvr, vr_b, rel, 8, 256*512, 512, 1936, 1424);
  }

  // lin: concat(s,o) @ lin_w^T -> z1
  {
    GP g{}; g.A = s_mat; g.A2 = o_mat; g.B = lin_w; g.bias = lin_b; g.C = z1;
    g.M = 256; g.N = 712; g.K = 1424; g.ldc = 712; g.coff = 0; g.kChunk = 1424;
    gemm_k<3><<<dim3(12,4,1), blk, 0, stream>>>(g);
  }

  // bilinear: bf16-split MFMA, depth-2 pipeline, split-K 42 -> partials -> bilbuf
  bil_mfma_k<<<dim3(12, 2, BILSPLIT), dim3(256), 0, stream>>>(s_mat, o_mat, bil_w, pbil);
  reduce_k<<<dim3(712), blk, 0, stream>>>(pbil, bil_b, bilbuf, BILSPLIT, 256*712, 712, 712, 0);

  // proj: relu(concat(z1,bil)) @ proj_w^T -> rel[:,0:1424]
  {
    GP g{}; g.A = z1; g.A2 = bilbuf; g.B = proj_w; g.bias = proj_b; g.C = rel;
    g.M = 256; g.N = 1424; g.K = 1424; g.ldc = 1936; g.coff = 0; g.kChunk = 1424;
    gemm_k<4><<<dim3(23,4,1), blk, 0, stream>>>(g);
  }

  // segments, memory zero + mask, scatter, pooled max
  seg_k<<<dim3(1), blk, 0, stream>>>(im_idx, counts, starts, pos);
  zeromask_k<<<dim3((SZ_MEM + SZ_MASK + 255)/256), blk, 0, stream>>>(out, counts);
  scatter_k<<<dim3(256), blk, 0, stream>>>(rel, pos, im_idx, out);
  pooled_k<<<dim3(8,16), blk, 0, stream>>>(rel, starts, counts, out);

  // act = sigmoid(pooled @ ac_w^T + ac_b)
  {
    GP g{}; g.A = out + OFF_POOLED; g.B = ac_w; g.bias = ac_b; g.C = out + OFF_ACT;
    g.M = 16; g.N = 157; g.K = 1936; g.ldc = 157; g.coff = 0; g.kChunk = 1936;
    gemm_k<8><<<dim3(3,1,1), blk, 0, stream>>>(g);
  }
}

// Round 7
// 3560.516 us; speedup vs baseline: 2.1307x; 1.0448x over previous
//
#include <hip/hip_runtime.h>
#include <math.h>

#define DEV __device__ __forceinline__

// ---- problem constants ----
#define PP    256          // pairs
#define BIMG  16
#define HB    712          // bilinear dim
#define KBIL  (712*712)    // 506944
#define DRELC 1936
#define NSPLIT 32          // h-chunks (split-K); grid 12*2*32=768 = 3 blocks/CU resident
#define HPER   23          // h per chunk (31*23=713 covers 712; block 31 nearly idle)
#define TSTEP  23          // t-steps of 32 per h panel (23*32=736, t padded 712->736)

// ---- d_out layout (floats) ----
#define SZ_ACT    (16*157)
#define OFF_ACT   0
#define OFF_POOLED (SZ_ACT)
#define SZ_POOLED (16*1936)
#define OFF_MEM   (OFF_POOLED + SZ_POOLED)
#define SZ_MEM    (24*16*1936)
#define OFF_MASK  (OFF_MEM + SZ_MEM)
#define SZ_MASK   (16*24)

// ---- ws layout (floats) ----
#define OFF_S     0
#define OFF_O     (OFF_S + 256*712)
#define OFF_Z1    (OFF_O + 256*712)
#define OFF_BIL   (OFF_Z1 + 256*712)
#define OFF_REL   (OFF_BIL + 256*712)
#define OFF_UBUF  (OFF_REL + 256*1936)
#define OFF_XP    (OFF_UBUF + 12544*256)
#define OFF_SHARED (OFF_XP + 256*128*49)
#define OFF_X1    OFF_SHARED                       // 256*128*196 floats
#define OFF_PVR   OFF_SHARED                       // 8*256*512
// pbil (32*256*712 = 5.83M floats) aliases ubuf+xp+shared (11.24M), all dead
// by the time the bilinear runs.
#define OFF_PBIL  OFF_UBUF
#define SZ_SHARED (256*128*196)                    // max(x1, pvr)
#define OFF_INTS  (OFF_SHARED + SZ_SHARED)
// bilinear prep buffers (after ints): o hi/lo bf16 [256][736], sT f32 [712][256]
#define OFF_OH    (OFF_INTS + 256)                 // 256*736 bf16 = 94208 floats
#define OFF_OL    (OFF_OH + 94208)
#define OFF_ST    (OFF_OL + 94208)                 // 712*256 floats

typedef __bf16 bf16x8 __attribute__((ext_vector_type(8)));
typedef float  f32x4  __attribute__((ext_vector_type(4)));

// ============================================================
// prep: split o into bf16 hi/lo (padded to 736 cols), transpose s.
// ============================================================
__global__ __launch_bounds__(256) void prep_k(const float* __restrict__ s,
    const float* __restrict__ o, __bf16* __restrict__ oh, __bf16* __restrict__ ol,
    float* __restrict__ sT) {
  int i = blockIdx.x*256 + threadIdx.x;
  if (i < 256*736) {
    int n = i / 736, t = i - n*736;
    float v = (t < 712) ? o[n*712 + t] : 0.f;
    __bf16 h = (__bf16)v;
    oh[i] = h;
    ol[i] = (__bf16)(v - (float)h);
  } else {
    int j = i - 256*736;
    if (j < 712*256) {
      int h = j >> 8, n = j & 255;
      sT[j] = s[n*712 + h];
    }
  }
}

// ============================================================
// Bilinear, h-factored: bil[n,c] = sum_h s[n,h] * (sum_t o[n,t]*W[c,h,t]).
// Inner GEMM (per h-panel, K=712 padded 736): A = o (pre-split bf16 hi/lo,
// loaded straight from global — ZERO per-step VALU A-build); W staged to LDS
// hi/lo bf16 per 32-t step; 3 MFMA terms ohi*whi + ohi*wlo + olo*whi.
// s applied as f32 rescale of the panel accumulator (gacc -> bacc).
// Barriers are raw s_barrier + lgkmcnt(0) only — global prefetch FIFO
// (depth 2) stays in flight across barriers (no vmcnt drain).
// Block: 128 rows x 64 cols, 4 waves. Grid (12,2,32) = 768 = 3/CU resident.
// ============================================================
__global__ __launch_bounds__(256, 3) void bil_mfma_k(
    const __bf16* __restrict__ oh, const __bf16* __restrict__ ol,
    const float* __restrict__ sT, const float* __restrict__ W,
    float* __restrict__ part) {
  __shared__ __align__(16) __bf16 Wsh[2][2][64*40];   // [buf][hi/lo][row*40+k]

  const int tid = threadIdx.x;
  const int C0 = blockIdx.x * 64;
  const int rowBase = blockIdx.y * 128;
  const int h0 = blockIdx.z * HPER;
  const int hEnd = min(712, h0 + HPER);
  const int nsteps = (hEnd > h0) ? (hEnd - h0) * TSTEP : 0;

  // staging role: 64 rows (lane) x 32 floats (wave selects 8-float chunk)
  const int srow = tid & 63;
  const int koff = (tid >> 6) * 8;
  const int sc = C0 + srow;

  // compute role
  const int wv = tid >> 6, lane = tid & 63;
  const int lr = lane & 15, lg = lane >> 4;
  const int n0 = rowBase + wv * 32 + lr;   // rf=0 row; rf=1 adds +16

  f32x4 bacc[2][4], gacc[2][4];
  #pragma unroll
  for (int a = 0; a < 2; a++)
    #pragma unroll
    for (int b = 0; b < 4; b++)
      #pragma unroll
      for (int i = 0; i < 4; i++) { bacc[a][b][i] = 0.f; gacc[a][b][i] = 0.f; }

  auto wload = [&](int hh, int zt, float4& va, float4& vb) {
    int t0 = zt * 32 + koff;
    if (sc < 712 && t0 < 712) {
      const float* p = W + (size_t)sc * KBIL + hh * 712 + t0;
      va = *(const float4*)p;
      vb = *(const float4*)(p + 4);
    } else {
      va = make_float4(0.f,0.f,0.f,0.f);
      vb = make_float4(0.f,0.f,0.f,0.f);
    }
  };
  auto wstore = [&](int buf, const float4& va, const float4& vb) {
    float t[8] = {va.x, va.y, va.z, va.w, vb.x, vb.y, vb.z, vb.w};
    bf16x8 hi, lo;
    #pragma unroll
    for (int i = 0; i < 8; i++) {
      float p = t[i];
      __bf16 h = (__bf16)p;
      hi[i] = h;
      lo[i] = (__bf16)(p - (float)h);
    }
    *(bf16x8*)&Wsh[buf][0][srow*40 + koff] = hi;
    *(bf16x8*)&Wsh[buf][1][srow*40 + koff] = lo;
  };
  auto aload = [&](int zt, bf16x8& ah0, bf16x8& al0, bf16x8& ah1, bf16x8& al1) {
    const int t0 = zt * 32 + lg * 8;                  // always in [0,736) (padded)
    ah0 = *(const bf16x8*)&oh[(size_t)n0 * 736 + t0];
    al0 = *(const bf16x8*)&ol[(size_t)n0 * 736 + t0];
    ah1 = *(const bf16x8*)&oh[(size_t)(n0 + 16) * 736 + t0];
    al1 = *(const bf16x8*)&ol[(size_t)(n0 + 16) * 736 + t0];
  };
  auto domfma = [&](int cur, bf16x8 ah0, bf16x8 al0, bf16x8 ah1, bf16x8 al1) {
    #pragma unroll
    for (int cf = 0; cf < 4; cf++) {
      bf16x8 bhi = *(const bf16x8*)&Wsh[cur][0][(cf*16 + lr)*40 + lg*8];
      bf16x8 blo = *(const bf16x8*)&Wsh[cur][1][(cf*16 + lr)*40 + lg*8];
      gacc[0][cf] = __builtin_amdgcn_mfma_f32_16x16x32_bf16(ah0, bhi, gacc[0][cf], 0, 0, 0);
      gacc[0][cf] = __builtin_amdgcn_mfma_f32_16x16x32_bf16(ah0, blo, gacc[0][cf], 0, 0, 0);
      gacc[0][cf] = __builtin_amdgcn_mfma_f32_16x16x32_bf16(al0, bhi, gacc[0][cf], 0, 0, 0);
      gacc[1][cf] = __builtin_amdgcn_mfma_f32_16x16x32_bf16(ah1, bhi, gacc[1][cf], 0, 0, 0);
      gacc[1][cf] = __builtin_amdgcn_mfma_f32_16x16x32_bf16(ah1, blo, gacc[1][cf], 0, 0, 0);
      gacc[1][cf] = __builtin_amdgcn_mfma_f32_16x16x32_bf16(al1, bhi, gacc[1][cf], 0, 0, 0);
    }
  };
  auto hfinish = [&](int hh) {
    const float* sp = sT + (size_t)hh * 256 + rowBase + wv * 32 + lg * 4;
    float4 sv0 = *(const float4*)sp;
    float4 sv1 = *(const float4*)(sp + 16);
    float s0v[4] = {sv0.x, sv0.y, sv0.z, sv0.w};
    float s1v[4] = {sv1.x, sv1.y, sv1.z, sv1.w};
    #pragma unroll
    for (int cf = 0; cf < 4; cf++)
      #pragma unroll
      for (int i = 0; i < 4; i++) {
        bacc[0][cf][i] += s0v[i] * gacc[0][cf][i];
        bacc[1][cf][i] += s1v[i] * gacc[1][cf][i];
        gacc[0][cf][i] = 0.f;
        gacc[1][cf][i] = 0.f;
      }
  };

  if (nsteps > 0) {
    // prologue: buf0 <- (h0,0); FIFO f0 <- (h0,1), f1 <- (h0,2)  [nsteps >= 23]
    float4 f0a, f0b, f1a, f1b;
    { float4 pa, pb; wload(h0, 0, pa, pb); wstore(0, pa, pb); }
    wload(h0, 1, f0a, f0b);
    wload(h0, 2, f1a, f1b);
    bf16x8 ah0, al0, ah1, al1;
    aload(0, ah0, al0, ah1, al1);
    asm volatile("s_waitcnt lgkmcnt(0)\n\ts_barrier" ::: "memory");

    int zt = 0, hh = h0;            // current step decomposition
    int zt3 = 2, hh3 = h0;          // decomposition of index zz+2 (FIFO head)
    for (int zz = 0; zz < nsteps; ++zz) {
      const int cur = zz & 1;
      const bool notlast = (zz + 1 < nsteps);
      bf16x8 nh0, nl0, nh1, nl1;
      const int ztn = (zt == TSTEP-1) ? 0 : zt + 1;
      if (notlast) aload(ztn, nh0, nl0, nh1, nl1);

      domfma(cur, ah0, al0, ah1, al1);
      if (zt == TSTEP-1) hfinish(hh);

      if (notlast) {
        wstore(cur ^ 1, f0a, f0b);                 // W(zz+1) -> other buf
        f0a = f1a; f0b = f1b;                      // rotate FIFO
        if (zz + 3 < nsteps) {                     // advance to index zz+3
          zt3 = (zt3 == TSTEP-1) ? 0 : zt3 + 1;
          if (zt3 == 0) hh3++;
        }
        wload(hh3, zt3, f1a, f1b);
        ah0 = nh0; al0 = nl0; ah1 = nh1; al1 = nl1;
      }
      zt = ztn; if (zt == 0) hh++;
      asm volatile("s_waitcnt lgkmcnt(0)\n\ts_barrier" ::: "memory");
    }
  }

  // ---- epilogue: partials [z][256][712] ----
  const int bz = blockIdx.z;
  #pragma unroll
  for (int rf = 0; rf < 2; rf++) {
    #pragma unroll
    for (int cf = 0; cf < 4; cf++) {
      const int c = C0 + cf*16 + lr;
      if (c >= 712) continue;
      #pragma unroll
      for (int i = 0; i < 4; i++) {
        const int n = rowBase + wv*32 + rf*16 + lg*4 + i;  // D: row=(lane>>4)*4+i
        part[((size_t)bz*256 + n)*712 + c] = bacc[rf][cf][i];
      }
    }
  }
}

struct GP {
  const float* A; const float* A2; const float* B; const float* bias;
  float* C;
  const int* gidx; int goff;
  int M, N, K;
  int ldc, coff;
  int kChunk;
  const float* bn_g; const float* bn_b; const float* bn_m; const float* bn_v;
};

// modes:
// 0: A row-gathered via gidx (features)         epi: +bias -> C
// 2: plain A (ubuf rows), plain B (vr_w)        epi: partial C[z][M][N]
// 3: A = concat(s,o)                            epi: +bias -> C
// 4: A = relu(concat(z1,bil))                   epi: +bias -> C
// 5: A = union_feat gather [(n,q)][ic]          epi: +bias -> ubuf[n][oc][q]
// 6: A = im2col(xp) 3x3 pad1                    epi: bn2(relu(+bias)) += ubuf[n][oc][q]
// 8: plain A                                    epi: sigmoid(+bias) -> C

template<int MODE>
DEV float loadA(const GP& p, int r, int k) {
  if (MODE == 0) { int fr = p.gidx[2*r + p.goff]; return p.A[fr*2048 + k]; }
  if (MODE == 2 || MODE == 8) return p.A[r*p.K + k];
  if (MODE == 3) return (k < 712) ? p.A[r*712 + k] : p.A2[r*712 + (k-712)];
  if (MODE == 4) { float v = (k < 712) ? p.A[r*712 + k] : p.A2[r*712 + (k-712)];
                   return fmaxf(v, 0.f); }
  if (MODE == 5) { int n = r/49, q = r - n*49; return p.A[(n*1024 + k)*49 + q]; }
  if (MODE == 6) {
    int n = r/49, q = r - n*49; int py = q/7, px = q - py*7;
    int ic = k/9, k9 = k - ic*9; int dy = k9/3, dx = k9 - dy*3;
    int iy = py + dy - 1, ix = px + dx - 1;
    if ((unsigned)iy >= 7u || (unsigned)ix >= 7u) return 0.f;
    return p.A[(n*128 + ic)*49 + iy*7 + ix];
  }
  return 0.f;
}

template<int MODE>
DEV float loadB(const GP& p, int c, int k) {
  return p.B[c*p.K + k];
}

template<int MODE>
__global__ __launch_bounds__(256) void gemm_k(GP p) {
  __shared__ float As[16][68];
  __shared__ float Bs[16][68];
  const int tid = threadIdx.x;
  const int tx = tid & 15, ty = tid >> 4;
  const int col0 = blockIdx.x * 64, row0 = blockIdx.y * 64;
  const int kStart = blockIdx.z * p.kChunk;
  const int kEnd = min(p.K, kStart + p.kChunk);
  float acc[4][4] = {};

  for (int kb = kStart; kb < kEnd; kb += 16) {
    if (MODE == 5 || MODE == 6) {
      int r = tid & 63, kk0 = tid >> 6;
      #pragma unroll
      for (int i = 0; i < 4; i++) {
        int kk = kk0 + i*4;
        int gr = row0 + r, gk = kb + kk;
        float v = 0.f;
        if (gr < p.M && gk < kEnd) v = loadA<MODE>(p, gr, gk);
        As[kk][r] = v;
      }
    } else {
      int kk = tid & 15, r0 = tid >> 4;
      #pragma unroll
      for (int i = 0; i < 4; i++) {
        int r = r0 + i*16;
        int gr = row0 + r, gk = kb + kk;
        float v = 0.f;
        if (gr < p.M && gk < kEnd) v = loadA<MODE>(p, gr, gk);
        As[kk][r] = v;
      }
    }
    {
      int kk = tid & 15, c0 = tid >> 4;
      #pragma unroll
      for (int i = 0; i < 4; i++) {
        int c = c0 + i*16;
        int gc = col0 + c, gk = kb + kk;
        float v = 0.f;
        if (gc < p.N && gk < kEnd) v = loadB<MODE>(p, gc, gk);
        Bs[kk][c] = v;
      }
    }
    __syncthreads();
    #pragma unroll
    for (int kk = 0; kk < 16; kk++) {
      float a[4], b[4];
      #pragma unroll
      for (int j = 0; j < 4; j++) a[j] = As[kk][ty*4 + j];
      #pragma unroll
      for (int j = 0; j < 4; j++) b[j] = Bs[kk][tx*4 + j];
      #pragma unroll
      for (int i = 0; i < 4; i++)
        #pragma unroll
        for (int j = 0; j < 4; j++) acc[i][j] += a[i]*b[j];
    }
    __syncthreads();
  }

  #pragma unroll
  for (int i = 0; i < 4; i++) {
    int r = row0 + ty*4 + i;
    if (r >= p.M) continue;
    #pragma unroll
    for (int j = 0; j < 4; j++) {
      int c = col0 + tx*4 + j;
      if (c >= p.N) continue;
      float v = acc[i][j];
      if (MODE == 2) {
        p.C[(size_t)blockIdx.z * p.M * p.N + (size_t)r * p.N + c] = v;
      } else if (MODE == 5) {
        int n = r/49, q = r - n*49;
        p.C[n*12544 + c*49 + q] = v + p.bias[c];
      } else if (MODE == 6) {
        int n = r/49, q = r - n*49;
        float sc = p.bn_g[c] / sqrtf(p.bn_v[c] + 1e-5f);
        float sh = p.bn_b[c] - p.bn_m[c]*sc;
        float t2 = fmaxf(v + p.bias[c], 0.f)*sc + sh;
        p.C[n*12544 + c*49 + q] += t2;
      } else if (MODE == 8) {
        float t2 = v + p.bias[c];
        p.C[r*p.ldc + p.coff + c] = 1.f/(1.f + expf(-t2));
      } else {
        p.C[r*p.ldc + p.coff + c] = v + p.bias[c];
      }
    }
  }
}

__global__ __launch_bounds__(256) void reduce_k(const float* __restrict__ part,
    const float* __restrict__ bias, float* __restrict__ out,
    int S, int MN, int N, int ldc, int coff) {
  int i = blockIdx.x*256 + threadIdx.x;
  if (i >= MN) return;
  float s = 0.f;
  for (int z = 0; z < S; z++) s += part[(size_t)z*MN + i];
  int r = i / N, c = i - r*N;
  out[r*ldc + coff + c] = s + bias[c];
}

__global__ __launch_bounds__(256) void emb_k(const int* __restrict__ pi,
    const int* __restrict__ labels, const float* __restrict__ e1,
    const float* __restrict__ e2, float* __restrict__ s, float* __restrict__ o) {
  int i = blockIdx.x*256 + threadIdx.x;
  if (i >= 2*256*200) return;
  int which = i / (256*200); int rest = i - which*(256*200);
  int n = rest / 200; int j = rest - n*200;
  int lab = labels[pi[2*n + which]];
  float v = which ? e2[lab*200 + j] : e1[lab*200 + j];
  (which ? o : s)[n*712 + 512 + j] = v;
}

__global__ __launch_bounds__(256) void conv1_k(const float* __restrict__ in,
    const float* __restrict__ w, const float* __restrict__ bias,
    const float* __restrict__ g, const float* __restrict__ bt,
    const float* __restrict__ m, const float* __restrict__ vv,
    float* __restrict__ out) {
  int idx = blockIdx.x*256 + threadIdx.x;
  if (idx >= 256*128*14) return;
  int oy = idx % 14; int t = idx / 14; int c = t & 127; int n = t >> 7;
  float acc[14];
  float b0 = bias[c];
  #pragma unroll
  for (int ox = 0; ox < 14; ox++) acc[ox] = b0;
  for (int ci = 0; ci < 2; ci++) {
    #pragma unroll
    for (int ky = 0; ky < 7; ky++) {
      int iy = oy*2 - 3 + ky;
      if ((unsigned)iy >= 27u) continue;
      const float* ir = in + ((n*2 + ci)*27 + iy)*27;
      const float* wr = w + ((c*2 + ci)*7 + ky)*7;
      float iv[27];
      #pragma unroll
      for (int x = 0; x < 27; x++) iv[x] = ir[x];
      float wk[7];
      #pragma unroll
      for (int kx = 0; kx < 7; kx++) wk[kx] = wr[kx];
      #pragma unroll
      for (int kx = 0; kx < 7; kx++)
        #pragma unroll
        for (int ox = 0; ox < 14; ox++) {
          int ix = ox*2 - 3 + kx;
          if (ix >= 0 && ix < 27) acc[ox] += iv[ix]*wk[kx];
        }
    }
  }
  float sc = g[c] / sqrtf(vv[c] + 1e-5f);
  float sh = bt[c] - m[c]*sc;
  float* orow = out + ((n*128 + c)*14 + oy)*14;
  #pragma unroll
  for (int ox = 0; ox < 14; ox++) orow[ox] = fmaxf(acc[ox], 0.f)*sc + sh;
}

__global__ __launch_bounds__(256) void pool_k(const float* __restrict__ x1,
                                              float* __restrict__ xp) {
  int idx = blockIdx.x*256 + threadIdx.x;
  if (idx >= 256*128*49) return;
  int px = idx % 7; int t = idx / 7; int py = t % 7; t /= 7;
  int c = t & 127; int n = t >> 7;
  float mx = -INFINITY;
  for (int dy = 0; dy < 3; dy++) {
    int y = py*2 - 1 + dy;
    if ((unsigned)y >= 14u) continue;
    for (int dx = 0; dx < 3; dx++) {
      int x = px*2 - 1 + dx;
      if ((unsigned)x >= 14u) continue;
      mx = fmaxf(mx, x1[((n*128 + c)*14 + y)*14 + x]);
    }
  }
  xp[((n*128 + c)*7 + py)*7 + px] = mx;
}

__global__ __launch_bounds__(256) void seg_k(const int* __restrict__ im,
    int* __restrict__ counts, int* __restrict__ starts, int* __restrict__ pos) {
  __shared__ int c[16], s[16];
  int tid = threadIdx.x;
  if (tid < 16) c[tid] = 0;
  __syncthreads();
  atomicAdd(&c[im[tid]], 1);
  __syncthreads();
  if (tid == 0) { int run = 0; for (int b = 0; b < 16; b++) { s[b] = run; run += c[b]; } }
  __syncthreads();
  if (tid < 16) { counts[tid] = c[tid]; starts[tid] = s[tid]; }
  pos[tid] = tid - s[im[tid]];
}

__global__ __launch_bounds__(256) void zeromask_k(float* __restrict__ out,
                                                  const int* __restrict__ counts) {
  int i = blockIdx.x*256 + threadIdx.x;
  if (i < SZ_MEM) { out[OFF_MEM + i] = 0.f; return; }
  int j = i - SZ_MEM;
  if (j < SZ_MASK) {
    int b = j / 24, l = j - b*24;
    out[OFF_MASK + j] = (l >= counts[b]) ? 1.f : 0.f;
  }
}

__global__ __launch_bounds__(256) void scatter_k(const float* __restrict__ rel,
    const int* __restrict__ pos, const int* __restrict__ im, float* __restrict__ out) {
  int n = blockIdx.x;
  int l = pos[n], b = im[n];
  float* dst = out + OFF_MEM + ((size_t)l*16 + b)*1936;
  const float* src = rel + (size_t)n*1936;
  for (int d = threadIdx.x; d < 1936; d += 256) dst[d] = src[d];
}

__global__ __launch_bounds__(256) void pooled_k(const float* __restrict__ rel,
    const int* __restrict__ starts, const int* __restrict__ counts,
    float* __restrict__ out) {
  int b = blockIdx.y;
  int d = blockIdx.x*256 + threadIdx.x;
  if (d >= 1936) return;
  int st = starts[b], ct = counts[b];
  float mx = -INFINITY;
  for (int i = 0; i < ct; i++) mx = fmaxf(mx, rel[(size_t)(st + i)*1936 + d]);
  out[OFF_POOLED + b*1936 + d] = mx;
}

extern "C" void kernel_launch(void* const* d_in, const int* in_sizes, int n_in,
                              void* d_out, int out_size, void* d_ws, size_t ws_size,
                              hipStream_t stream) {
  const float* features   = (const float*)d_in[0];
  const int*   pair_idx   = (const int*)d_in[1];
  const int*   im_idx     = (const int*)d_in[2];
  const int*   labels     = (const int*)d_in[3];
  const float* union_feat = (const float*)d_in[4];
  const float* spatial    = (const float*)d_in[5];
  const float* w_union    = (const float*)d_in[6];
  const float* b_union    = (const float*)d_in[7];
  const float* conv1_w    = (const float*)d_in[8];
  const float* conv1_b    = (const float*)d_in[9];
  const float* bn1_g      = (const float*)d_in[10];
  const float* bn1_b      = (const float*)d_in[11];
  const float* bn1_m      = (const float*)d_in[12];
  const float* bn1_v      = (const float*)d_in[13];
  const float* conv2_w    = (const float*)d_in[14];
  const float* conv2_b    = (const float*)d_in[15];
  const float* bn2_g      = (const float*)d_in[16];
  const float* bn2_b      = (const float*)d_in[17];
  const float* bn2_m      = (const float*)d_in[18];
  const float* bn2_v      = (const float*)d_in[19];
  const float* subj_w     = (const float*)d_in[20];
  const float* subj_b     = (const float*)d_in[21];
  const float* obj_w      = (const float*)d_in[22];
  const float* obj_b      = (const float*)d_in[23];
  const float* vr_w       = (const float*)d_in[24];
  const float* vr_b       = (const float*)d_in[25];
  const float* emb1       = (const float*)d_in[26];
  const float* emb2       = (const float*)d_in[27];
  const float* bil_w      = (const float*)d_in[28];
  const float* bil_b      = (const float*)d_in[29];
  const float* lin_w      = (const float*)d_in[30];
  const float* lin_b      = (const float*)d_in[31];
  const float* proj_w     = (const float*)d_in[32];
  const float* proj_b     = (const float*)d_in[33];
  const float* ac_w       = (const float*)d_in[34];
  const float* ac_b       = (const float*)d_in[35];

  float* ws = (float*)d_ws;
  float* s_mat  = ws + OFF_S;
  float* o_mat  = ws + OFF_O;
  float* z1     = ws + OFF_Z1;
  float* bilbuf = ws + OFF_BIL;
  float* rel    = ws + OFF_REL;
  float* ubuf   = ws + OFF_UBUF;   // layout [n][oc][q] = [256][256][49]
  float* x1     = ws + OFF_X1;
  float* xp     = ws + OFF_XP;
  float* pvr    = ws + OFF_PVR;
  float* pbil   = ws + OFF_PBIL;
  int*   ints   = (int*)(ws + OFF_INTS);
  __bf16* ohp   = (__bf16*)(ws + OFF_OH);
  __bf16* olp   = (__bf16*)(ws + OFF_OL);
  float* sTp    = ws + OFF_ST;
  int* counts = ints; int* starts = ints + 16; int* pos = ints + 32;
  float* out = (float*)d_out;

  dim3 blk(256);

  // subj / obj linears (gathered rows of features) -> s_mat/o_mat cols [0,512)
  {
    GP g{}; g.A = features; g.B = subj_w; g.bias = subj_b; g.C = s_mat;
    g.gidx = pair_idx; g.goff = 0; g.M = 256; g.N = 512; g.K = 2048;
    g.ldc = 712; g.coff = 0; g.kChunk = 2048;
    gemm_k<0><<<dim3(8,4,1), blk, 0, stream>>>(g);
    g.goff = 1; g.B = obj_w; g.bias = obj_b; g.C = o_mat;
    gemm_k<0><<<dim3(8,4,1), blk, 0, stream>>>(g);
  }
  // embedding concat -> cols [512,712)
  emb_k<<<dim3(400), blk, 0, stream>>>(pair_idx, labels, emb1, emb2, s_mat, o_mat);

  // union 1x1 conv as GEMM -> ubuf[n][oc][q] (scatter epilogue)
  {
    GP g{}; g.A = union_feat; g.B = w_union; g.bias = b_union; g.C = ubuf;
    g.M = 12544; g.N = 256; g.K = 1024; g.kChunk = 1024;
    gemm_k<5><<<dim3(4,196,1), blk, 0, stream>>>(g);
  }

  // conv1 + relu + bn1 -> x1 ; maxpool -> xp
  conv1_k<<<dim3(1792), blk, 0, stream>>>(spatial, conv1_w, conv1_b,
                                          bn1_g, bn1_b, bn1_m, bn1_v, x1);
  pool_k<<<dim3(6272), blk, 0, stream>>>(x1, xp);

  // conv2 (implicit GEMM) + relu + bn2, accumulated into ubuf[n][oc][q]
  {
    GP g{}; g.A = xp; g.B = conv2_w; g.bias = conv2_b; g.C = ubuf;
    g.M = 12544; g.N = 256; g.K = 1152; g.kChunk = 1152;
    g.bn_g = bn2_g; g.bn_b = bn2_b; g.bn_m = bn2_m; g.bn_v = bn2_v;
    gemm_k<6><<<dim3(4,196,1), blk, 0, stream>>>(g);
  }

  // vr linear: ubuf [256][12544] contiguous rows x vr_w [512][12544]
  // (split-K 8) -> partials -> rel[:,1424:1936]
  {
    GP g{}; g.A = ubuf; g.B = vr_w; g.C = pvr;
    g.M = 256; g.N = 512; g.K = 12544; g.kChunk = 1568;
    gemm_k<2><<<dim3(8,4,8), blk, 0, stream>>>(g);
    reduce_k<<<dim3(512), blk, 0, stream>>>(pvr, vr_b, rel, 8, 256*512, 512, 1936, 1424);
  }

  // lin: concat(s,o) @ lin_w^T -> z1
  {
    GP g{}; g.A = s_mat; g.A2 = o_mat; g.B = lin_w; g.bias = lin_b; g.C = z1;
    g.M = 256; g.N = 712; g.K = 1424; g.ldc = 712; g.coff = 0; g.kChunk = 1424;
    gemm_k<3><<<dim3(12,4,1), blk, 0, stream>>>(g);
  }

  // bilinear: prep (o split + s transpose), h-factored MFMA, split over 32 h-chunks
  prep_k<<<dim3((256*736 + 712*256 + 255)/256), blk, 0, stream>>>(s_mat, o_mat, ohp, olp, sTp);
  bil_mfma_k<<<dim3(12, 2, NSPLIT), dim3(256), 0, stream>>>(ohp, olp, sTp, bil_w, pbil);
  reduce_k<<<dim3(712), blk, 0, stream>>>(pbil, bil_b, bilbuf, NSPLIT, 256*712, 712, 712, 0);

  // proj: relu(concat(z1,bil)) @ proj_w^T -> rel[:,0:1424]
  {
    GP g{}; g.A = z1; g.A2 = bilbuf; g.B = proj_w; g.bias = proj_b; g.C = rel;
    g.M = 256; g.N = 1424; g.K = 1424; g.ldc = 1936; g.coff = 0; g.kChunk = 1424;
    gemm_k<4><<<dim3(23,4,1), blk, 0, stream>>>(g);
  }

  // segments, memory zero + mask, scatter, pooled max
  seg_k<<<dim3(1), blk, 0, stream>>>(im_idx, counts, starts, pos);
  zeromask_k<<<dim3((SZ_MEM + SZ_MASK + 255)/256), blk, 0, stream>>>(out, counts);
  scatter_k<<<dim3(256), blk, 0, stream>>>(rel, pos, im_idx, out);
  pooled_k<<<dim3(8,16), blk, 0, stream>>>(rel, starts, counts, out);

  // act = sigmoid(pooled @ ac_w^T + ac_b)
  {
    GP g{}; g.A = out + OFF_POOLED; g.B = ac_w; g.bias = ac_b; g.C = out + OFF_ACT;
    g.M = 16; g.N = 157; g.K = 1936; g.ldc = 157; g.coff = 0; g.kChunk = 1936;
    gemm_k<8><<<dim3(3,1,1), blk, 0, stream>>>(g);
  }
}